// Round 6
// baseline (261.692 us; speedup 1.0000x reference)
//
#include <hip/hip_runtime.h>
#include <math.h>

// Problem constants
#define BB 32
#define SS 50
#define LL 16
#define CC 50
#define DD 64
#define NCH 13           // c-chunks of 4 rows (C=50 padded to 52)
#define H4 256
#define NROWS_Q (BB*SS)            // 1600
#define NROWS_L (BB*SS*LL)         // 25600

#define EA_ST 2304       // floats per (b,s) ea record: 17 slots * 128, padded
#define W_ST  68         // floats per (b,om,s) w record: 17 * 4

// GEMM geometry for k0
#define RB 64                       // rows per block
#define NBLK_L (NROWS_L/RB)         // 400
#define NBLK_Q (NROWS_Q/RB)         // 25
#define NGB (NBLK_L + 2*NBLK_Q)     // 450

// phaseB W-staging geometry
#define KC 32                       // k-rows per staged chunk (32 KB)
#define NKC (H4/KC)                 // 8 chunks

// Layout invariants shared by k0 (producer) and phaseA (consumer)
static_assert(EA_ST == 17*128 + 128, "ea record: 17 slots x 64 lanes x float2, +pad");
static_assert(W_ST == 17*4, "w record: 17 slots x 4 chunk-cols");
static_assert(SS % 2 == 0, "phaseA double-step pipeline needs even SS");
static_assert(NROWS_L % RB == 0 && NROWS_Q % RB == 0, "GEMM row blocking");
static_assert(KC*H4/4 % 256 == 0, "phaseB chunk = whole float4s per thread");

// ---------------- workspace layout (floats) ----------------
#define OFF_EA     ((size_t)0)
#define OFF_W      (OFF_EA + (size_t)NROWS_Q*EA_ST)
#define OFF_PQ     (OFF_W  + (size_t)BB*NCH*SS*W_ST)
#define OFF_PL     (OFF_PQ + (size_t)NROWS_Q*DD)
#define OFF_QE     (OFF_PL + (size_t)NROWS_Q*DD)
#define OFF_LELAST (OFF_QE + (size_t)NROWS_Q*DD)
// total = 5,510,400 floats = 22.0 MB

// =====================================================================
// K0: all row-parallel precompute as ONE register-tile GEMM + row stage.
// (unchanged from round 4)
// =====================================================================
__global__ __launch_bounds__(256) void k0_kernel(
    const int* __restrict__ qd, const int* __restrict__ qadx,
    const int* __restrict__ ld,
    const float* __restrict__ Kmat, const float* __restrict__ qemb,
    const float* __restrict__ qaemb,
    const float* __restrict__ We, const float* __restrict__ Wa,
    const float* __restrict__ be, const float* __restrict__ ba,
    float* __restrict__ eaW, float* __restrict__ wrecW,
    float* __restrict__ Pzero,          // Pq base; Pq+Pl contiguous
    float* __restrict__ q_e_o, float* __restrict__ le_last)
{
    __shared__ float smem[16384];       // 64 KB: [X 16K | W 48K -> Out 48K]
    float* sX   = smem;                 // [64][64]
    float* sW   = smem + 4096;          // [16][192][4] k4-interleaved
    float* sOut = smem + 4096;          // aliases sW after the k-loop: [64][192]

    int tid = threadIdx.x;
    int bid = blockIdx.x;

    // zero the phaseA atomic accumulators (Pq,Pl contiguous)
    for (int i = bid*256 + tid; i < 2*NROWS_Q*DD; i += NGB*256) Pzero[i] = 0.f;

    int bt, base;
    if (bid < NBLK_L)              { bt = 0; base = bid*RB; }
    else if (bid < NBLK_L+NBLK_Q)  { bt = 1; base = (bid-NBLK_L)*RB; }
    else                           { bt = 2; base = (bid-NBLK_L-NBLK_Q)*RB; }

    // ---- stage X tile (embedding gather) ----
    {
        const int*   idsrc = (bt==0) ? ld : (bt==1) ? qd : qadx;
        const float* tab   = (bt==2) ? qaemb : qemb;
        for (int idx = tid; idx < RB*16; idx += 256) {
            int r = idx >> 4, q = idx & 15;
            int id = idsrc[base + r];
            *(float4*)(sX + r*64 + q*4) =
                *(const float4*)(tab + (size_t)id*DD + q*4);
        }
    }
    // ---- stage Wcat (k4-interleaved) ----
    for (int i = tid; i < 12288; i += 256) {
        int k4 = i / 768, rem = i - k4*768;
        int c = rem >> 2, j = rem & 3;
        int k = k4*4 + j;
        float v;
        if      (c < 64)  v = We[k*64 + c];
        else if (c < 128) v = Wa[k*64 + (c-64)];
        else if (c < 178) v = Kmat[(c-128)*64 + k];
        else              v = 0.f;
        sW[i] = v;
    }
    __syncthreads();

    // ---- GEMM: out[r][c] = sum_k X[r][k]*Wcat[k][c] ----
    int rg = tid >> 5, cg = tid & 31;
    int r0 = rg*8, c0 = cg*6;
    float acc[8][6];
    #pragma unroll
    for (int i = 0; i < 8; ++i)
        #pragma unroll
        for (int c = 0; c < 6; ++c) acc[i][c] = 0.f;

    #pragma unroll 2
    for (int k4 = 0; k4 < 16; ++k4) {
        float4 xv[8], wv[6];
        #pragma unroll
        for (int i = 0; i < 8; ++i)
            xv[i] = *(const float4*)(sX + (r0+i)*64 + k4*4);
        #pragma unroll
        for (int c = 0; c < 6; ++c)
            wv[c] = *(const float4*)(sW + k4*768 + (c0+c)*4);
        #pragma unroll
        for (int i = 0; i < 8; ++i)
            #pragma unroll
            for (int c = 0; c < 6; ++c) {
                acc[i][c] = fmaf(xv[i].x, wv[c].x, acc[i][c]);
                acc[i][c] = fmaf(xv[i].y, wv[c].y, acc[i][c]);
                acc[i][c] = fmaf(xv[i].z, wv[c].z, acc[i][c]);
                acc[i][c] = fmaf(xv[i].w, wv[c].w, acc[i][c]);
            }
    }
    __syncthreads();            // all waves done reading sW
    #pragma unroll
    for (int i = 0; i < 8; ++i)
        #pragma unroll
        for (int c = 0; c < 6; ++c)
            sOut[(r0+i)*192 + c0 + c] = acc[i][c];
    __syncthreads();

    // ---- stage 2: per-row nonlinearity + packing; wave per row ----
    int lane = tid & 63, wvi = tid >> 6;
    float bev = be[lane], bav = ba[lane];

    auto rowsoftmax = [&](const float* orow) -> float {
        float sc = orow[128 + lane];
        float s = (lane < CC) ? sc : -1e30f;
        float mx = s;
        #pragma unroll
        for (int o = 32; o >= 1; o >>= 1) mx = fmaxf(mx, __shfl_xor(mx, o));
        float p = (lane < CC) ? expf(s - mx) : 0.f;
        float sum = p;
        #pragma unroll
        for (int o = 32; o >= 1; o >>= 1) sum += __shfl_xor(sum, o);
        return p / sum;
    };

    for (int i = 0; i < 16; ++i) {
        int rr = wvi*16 + i;
        int grow = base + rr;
        const float* orow = sOut + rr*192;

        if (bt == 0) {
            float erv = 1.f / (1.f + expf(-(orow[lane] + bev)));
            float adv = tanhf(orow[64 + lane] + bav);
            float wsm = rowsoftmax(orow);
            int bs = grow >> 4, il = grow & 15;
            *(float2*)(eaW + (size_t)bs*EA_ST + il*128 + lane*2) =
                make_float2(erv, adv);
            int b = bs / SS, s2 = bs - b*SS;
            if (lane < 52) {
                int omx = lane >> 2, j = lane & 3;
                wrecW[(((size_t)(b*NCH + omx)*SS + s2)*17 + il)*4 + j] =
                    (lane < CC) ? wsm : 0.f;
            }
            if (il == LL-1) le_last[(size_t)bs*DD + lane] = sX[rr*64 + lane];
        } else if (bt == 1) {
            float wsm = rowsoftmax(orow);
            int qrow = grow;
            int b = qrow / SS, s2 = qrow - b*SS;
            if (lane < 52) {
                int omx = lane >> 2, j = lane & 3;
                wrecW[(((size_t)(b*NCH + omx)*SS + s2)*17 + 16)*4 + j] =
                    (lane < CC) ? wsm : 0.f;
            }
            q_e_o[(size_t)qrow*DD + lane] = sX[rr*64 + lane];
        } else {
            float erv = 1.f / (1.f + expf(-(orow[lane] + bev)));
            float adv = tanhf(orow[64 + lane] + bav);
            int qrow = grow;
            *(float2*)(eaW + (size_t)qrow*EA_ST + 2048 + lane*2) =
                make_float2(erv, adv);
        }
    }
}

// =====================================================================
// Phase A: sequential scan (unchanged from round 4).
// =====================================================================
__global__ __launch_bounds__(64) void phaseA_kernel(
    const float* __restrict__ M0,
    const float* __restrict__ ea, const float* __restrict__ wrec,
    float* __restrict__ Pq, float* __restrict__ Pl)
{
    int om   = blockIdx.x >> 5;     // 0..12
    int b    = blockIdx.x & 31;     // 0..31
    int lane = threadIdx.x;
    int c0   = om * 4;

    __shared__ __align__(16) float wbuf[2][W_ST];

    float M[4];
    #pragma unroll
    for (int i = 0; i < 4; ++i) {
        int c = c0 + i;
        M[i] = (c < CC) ? M0[c*DD + lane] : 0.f;
    }

    const float* eb = ea   + (size_t)b*SS*EA_ST + lane*2;
    const float* wb = wrec + (size_t)(b*NCH + om)*SS*W_ST;
    float* pq = Pq + (size_t)b*SS*DD + lane;
    float* pl = Pl + (size_t)b*SS*DD + lane;

    float2 ea0[17], ea1[17];

    // prologue: load step 0 (ea -> regs, w -> wbuf[0])
    #pragma unroll
    for (int il = 0; il < 17; ++il)
        ea0[il] = *(const float2*)(eb + il*128);
    if (lane < 17)
        *(float4*)&wbuf[0][lane*4] = *(const float4*)(wb + lane*4);

    auto step = [&](int s, float2 (&cur)[17], float2 (&nxt)[17], int wbsel) {
        bool pf = (s < SS-1);
        float4 rw;
        if (pf) {
            const float* eg = eb + (size_t)(s+1)*EA_ST;
            #pragma unroll
            for (int il = 0; il < 17; ++il)
                nxt[il] = *(const float2*)(eg + il*128);
            if (lane < 17)
                rw = *(const float4*)(wb + (size_t)(s+1)*W_ST + lane*4);
        }

        // ---- compute step s ----
        float4 qw = *(const float4*)&wbuf[wbsel][64];   // q-chunk w (slot 16)
        float qr;
        qr = qw.x * M[0];
        qr = fmaf(qw.y, M[1], qr);
        qr = fmaf(qw.z, M[2], qr);
        qr = fmaf(qw.w, M[3], qr);

        float a0 = 0.f, a1 = 0.f, a2 = 0.f, a3 = 0.f;
        #pragma unroll
        for (int il = 0; il < 16; ++il) {
            float4 w = *(const float4*)&wbuf[wbsel][il*4];
            float e = cur[il].x, a = cur[il].y;
            a0 = fmaf(w.x, M[0], a0);
            a1 = fmaf(w.y, M[1], a1);
            a2 = fmaf(w.z, M[2], a2);
            a3 = fmaf(w.w, M[3], a3);
            M[0] = fmaf(w.x, fmaf(-e, M[0], a), M[0]);
            M[1] = fmaf(w.y, fmaf(-e, M[1], a), M[1]);
            M[2] = fmaf(w.z, fmaf(-e, M[2], a), M[2]);
            M[3] = fmaf(w.w, fmaf(-e, M[3], a), M[3]);
        }

        atomicAdd(pq + (size_t)s*DD, qr);
        atomicAdd(pl + (size_t)s*DD, (a0 + a1) + (a2 + a3));

        { // final q-write
            float e = cur[16].x, a = cur[16].y;
            M[0] = fmaf(qw.x, fmaf(-e, M[0], a), M[0]);
            M[1] = fmaf(qw.y, fmaf(-e, M[1], a), M[1]);
            M[2] = fmaf(qw.z, fmaf(-e, M[2], a), M[2]);
            M[3] = fmaf(qw.w, fmaf(-e, M[3], a), M[3]);
        }

        // write next w-record late (vmcnt wait lands after compute)
        if (pf && lane < 17)
            *(float4*)&wbuf[wbsel ^ 1][lane*4] = rw;
    };

    for (int s = 0; s < SS; s += 2) {
        step(s,     ea0, ea1, 0);
        step(s + 1, ea1, ea0, 1);
    }
}

// =====================================================================
// Phase B v2: mastery -> LN -> MLP -> sigmoid -> out.
// 8 rows per 256-thread block, 200 blocks.
// W0/W1 staged into LDS in KC=32-row chunks (32 KB) via bulk coalesced
// float4 loads prefetched into registers one chunk ahead (issue-early,
// write-late). Compute is pure LDS + VALU: per k4, 4 conflict-free b32
// w-reads + 8 broadcast b128 m-reads + 32 FMAs. No dependent L2 loads
// in the k-loop -> not latency-bound even at 1 wave/SIMD.
// =====================================================================
__global__ __launch_bounds__(256) void phaseB_kernel(
    const float* __restrict__ Pq, const float* __restrict__ Pl,
    const float* __restrict__ q_e_i, const float* __restrict__ le_last,
    const float* __restrict__ ln_g, const float* __restrict__ ln_b,
    const float* __restrict__ W0, const float* __restrict__ b0,
    const float* __restrict__ W1, const float* __restrict__ b1,
    const float* __restrict__ Wout, const float* __restrict__ bout,
    float* __restrict__ out)
{
    __shared__ float m[8][H4];          // 8 KB
    __shared__ float h[8][H4];          // 8 KB
    __shared__ float sW[KC*H4];         // 32 KB staged W chunk
    __shared__ float red[8][4];

    int j = threadIdx.x;                // owns output column j
    int g0 = blockIdx.x * 8;
    int lane = j & 63, wv = j >> 6;

    // ---- issue W0 chunk-0 loads immediately (hide under build+LN) ----
    float4 pf[8];
    #pragma unroll
    for (int t = 0; t < 8; ++t)
        pf[t] = *(const float4*)(W0 + t*1024 + j*4);

    // ---- build mastery = [q_read | q_e | l_read | le_last] ----
    int seg = j >> 6, dd = j & 63;
    #pragma unroll
    for (int r = 0; r < 8; ++r) {
        int g = g0 + r;
        float v;
        if      (seg == 0) v = Pq[(size_t)g*DD + dd];
        else if (seg == 1) v = q_e_i[(size_t)g*DD + dd];
        else if (seg == 2) v = Pl[(size_t)g*DD + dd];
        else               v = le_last[(size_t)g*DD + dd];
        m[r][j] = v;
    }
    __syncthreads();

    // ---- LayerNorm: wave wv normalizes rows wv and wv+4 ----
    #pragma unroll
    for (int rr = 0; rr < 2; ++rr) {
        int r = wv + rr*4;
        float4 v4 = *(((const float4*)&m[r][0]) + lane);
        float s1 = v4.x + v4.y + v4.z + v4.w;
        float s2 = v4.x*v4.x + v4.y*v4.y + v4.z*v4.z + v4.w*v4.w;
        #pragma unroll
        for (int o = 32; o >= 1; o >>= 1) {
            s1 += __shfl_xor(s1, o);
            s2 += __shfl_xor(s2, o);
        }
        float mu  = s1 * (1.f/256.f);
        float var = s2 * (1.f/256.f) - mu*mu;
        float is  = rsqrtf(var + 1e-5f);
        float4 g4 = *(((const float4*)ln_g) + lane);
        float4 b4 = *(((const float4*)ln_b) + lane);
        float4 o4;
        o4.x = (v4.x - mu)*is*g4.x + b4.x;
        o4.y = (v4.y - mu)*is*g4.y + b4.y;
        o4.z = (v4.z - mu)*is*g4.z + b4.z;
        o4.w = (v4.w - mu)*is*g4.w + b4.w;
        *(((float4*)&m[r][0]) + lane) = o4;
    }
    __syncthreads();

    // ---- write W0 chunk 0 into LDS ----
    #pragma unroll
    for (int t = 0; t < 8; ++t)
        *(float4*)&sW[t*1024 + j*4] = pf[t];
    __syncthreads();

    // ---- GEMM1: acc = m @ W0 + b0, chunked over k ----
    float acc[8];
    {
        float bj = b0[j];
        #pragma unroll
        for (int r = 0; r < 8; ++r) acc[r] = bj;
    }
    for (int kc = 0; kc < NKC; ++kc) {
        // prefetch next chunk into regs (overlaps compute)
        if (kc + 1 < NKC) {
            const float* g = W0 + (size_t)(kc+1)*KC*H4;
            #pragma unroll
            for (int t = 0; t < 8; ++t)
                pf[t] = *(const float4*)(g + t*1024 + j*4);
        }
        // compute chunk kc from LDS
        #pragma unroll
        for (int k4 = 0; k4 < KC/4; ++k4) {
            int kb = kc*KC + k4*4;
            float w0 = sW[(k4*4+0)*H4 + j];
            float w1 = sW[(k4*4+1)*H4 + j];
            float w2 = sW[(k4*4+2)*H4 + j];
            float w3 = sW[(k4*4+3)*H4 + j];
            #pragma unroll
            for (int r = 0; r < 8; ++r) {
                float4 mv = *(const float4*)&m[r][kb];
                acc[r] = fmaf(mv.x, w0, acc[r]);
                acc[r] = fmaf(mv.y, w1, acc[r]);
                acc[r] = fmaf(mv.z, w2, acc[r]);
                acc[r] = fmaf(mv.w, w3, acc[r]);
            }
        }
        __syncthreads();
        if (kc + 1 < NKC) {
            #pragma unroll
            for (int t = 0; t < 8; ++t)
                *(float4*)&sW[t*1024 + j*4] = pf[t];
        }
        __syncthreads();
    }

    // ---- issue W1 chunk-0 loads, write h, stage W1 chunk 0 ----
    #pragma unroll
    for (int t = 0; t < 8; ++t)
        pf[t] = *(const float4*)(W1 + t*1024 + j*4);
    #pragma unroll
    for (int r = 0; r < 8; ++r) h[r][j] = fmaxf(acc[r], 0.f);
    __syncthreads();
    #pragma unroll
    for (int t = 0; t < 8; ++t)
        *(float4*)&sW[t*1024 + j*4] = pf[t];
    __syncthreads();

    // ---- GEMM2: a2 = h @ W1 + b1, chunked over k ----
    float a2[8];
    {
        float bj = b1[j];
        #pragma unroll
        for (int r = 0; r < 8; ++r) a2[r] = bj;
    }
    for (int kc = 0; kc < NKC; ++kc) {
        if (kc + 1 < NKC) {
            const float* g = W1 + (size_t)(kc+1)*KC*H4;
            #pragma unroll
            for (int t = 0; t < 8; ++t)
                pf[t] = *(const float4*)(g + t*1024 + j*4);
        }
        #pragma unroll
        for (int k4 = 0; k4 < KC/4; ++k4) {
            int kb = kc*KC + k4*4;
            float w0 = sW[(k4*4+0)*H4 + j];
            float w1 = sW[(k4*4+1)*H4 + j];
            float w2 = sW[(k4*4+2)*H4 + j];
            float w3 = sW[(k4*4+3)*H4 + j];
            #pragma unroll
            for (int r = 0; r < 8; ++r) {
                float4 hv = *(const float4*)&h[r][kb];
                a2[r] = fmaf(hv.x, w0, a2[r]);
                a2[r] = fmaf(hv.y, w1, a2[r]);
                a2[r] = fmaf(hv.z, w2, a2[r]);
                a2[r] = fmaf(hv.w, w3, a2[r]);
            }
        }
        __syncthreads();
        if (kc + 1 < NKC) {
            #pragma unroll
            for (int t = 0; t < 8; ++t)
                *(float4*)&sW[t*1024 + j*4] = pf[t];
        }
        __syncthreads();
    }

    // ---- pred = sigmoid(h1 . Wout + bout) ----
    float wo = Wout[j];
    #pragma unroll
    for (int r = 0; r < 8; ++r) {
        float v = a2[r] * wo;
        #pragma unroll
        for (int o = 32; o >= 1; o >>= 1) v += __shfl_xor(v, o);
        if (lane == 0) red[r][wv] = v;
    }
    __syncthreads();
    if (j < 8) {
        float t = red[j][0] + red[j][1] + red[j][2] + red[j][3] + bout[0];
        out[g0 + j] = 1.f / (1.f + expf(-t));
    }
}

// =====================================================================
extern "C" void kernel_launch(void* const* d_in, const int* in_sizes, int n_in,
                              void* d_out, int out_size, void* d_ws, size_t ws_size,
                              hipStream_t stream)
{
    const int*   q_data  = (const int*)  d_in[0];
    const int*   qa_data = (const int*)  d_in[1];
    const int*   l_data  = (const int*)  d_in[2];
    // d_in[3] users: unused by reference forward
    const float* Kmat    = (const float*)d_in[4];
    const float* q_embed = (const float*)d_in[5];
    const float* qa_embed= (const float*)d_in[6];
    // d_in[7] u_embed: unused by reference forward
    const float* M0      = (const float*)d_in[8];
    const float* W_e     = (const float*)d_in[9];
    const float* b_e     = (const float*)d_in[10];
    const float* W_a     = (const float*)d_in[11];
    const float* b_a     = (const float*)d_in[12];
    const float* ln_g    = (const float*)d_in[13];
    const float* ln_b    = (const float*)d_in[14];
    const float* W0      = (const float*)d_in[15];
    const float* b0      = (const float*)d_in[16];
    const float* W1      = (const float*)d_in[17];
    const float* b1      = (const float*)d_in[18];
    const float* W_out   = (const float*)d_in[19];
    const float* b_out   = (const float*)d_in[20];

    float* ws = (float*)d_ws;
    float* eaW     = ws + OFF_EA;
    float* wrecW   = ws + OFF_W;
    float* Pq      = ws + OFF_PQ;
    float* Pl      = ws + OFF_PL;
    float* q_e     = ws + OFF_QE;
    float* le_last = ws + OFF_LELAST;

    float* out = (float*)d_out;

    k0_kernel<<<NGB, 256, 0, stream>>>(q_data, qa_data, l_data,
                                       Kmat, q_embed, qa_embed,
                                       W_e, W_a, b_e, b_a,
                                       eaW, wrecW, Pq,
                                       q_e, le_last);
    phaseA_kernel<<<BB*NCH, 64, 0, stream>>>(M0, eaW, wrecW, Pq, Pl);
    phaseB_kernel<<<NROWS_Q/8, 256, 0, stream>>>(Pq, Pl, q_e, le_last,
                                                 ln_g, ln_b, W0, b0, W1, b1,
                                                 W_out, b_out, out);
}

// Round 8
// 211.819 us; speedup vs baseline: 1.2354x; 1.2354x over previous
//
#include <hip/hip_runtime.h>
#include <math.h>

// Problem constants
#define BB 32
#define SS 50
#define LL 16
#define CC 50
#define DD 64
#define NCH 13           // c-chunks of 4 rows (C=50 padded to 52)
#define H4 256
#define NROWS_Q (BB*SS)            // 1600
#define NROWS_L (BB*SS*LL)         // 25600

#define EA_ST 2304       // floats per (b,s) ea record: 17 slots * 128, padded
#define W_ST  68         // floats per (b,om,s) w record: 17 * 4

// GEMM geometry for k0
#define RB 64                       // rows per block
#define NBLK_L (NROWS_L/RB)         // 400
#define NBLK_Q (NROWS_Q/RB)         // 25
#define NGB (NBLK_L + 2*NBLK_Q)     // 450

// phaseB k-batching: 16 k-rows per register batch
#define KBAT 16
#define NBAT (H4/KBAT)              // 16 batches — MUST cover all of H4

// Layout invariants shared by k0 (producer) and phaseA (consumer)
static_assert(EA_ST == 17*128 + 128, "ea record: 17 slots x 64 lanes x float2, +pad");
static_assert(W_ST == 17*4, "w record: 17 slots x 4 chunk-cols");
static_assert(SS % 2 == 0, "phaseA double-step pipeline needs even SS");
static_assert(NROWS_L % RB == 0 && NROWS_Q % RB == 0, "GEMM row blocking");
static_assert(NBAT*KBAT == H4 && NBAT % 2 == 0,
              "phaseB k-loop must cover ALL of H4 in pairs of batches");

// ---------------- workspace layout (floats) ----------------
#define OFF_EA     ((size_t)0)
#define OFF_W      (OFF_EA + (size_t)NROWS_Q*EA_ST)
#define OFF_PQ     (OFF_W  + (size_t)BB*NCH*SS*W_ST)
#define OFF_PL     (OFF_PQ + (size_t)NROWS_Q*DD)
#define OFF_QE     (OFF_PL + (size_t)NROWS_Q*DD)
#define OFF_LELAST (OFF_QE + (size_t)NROWS_Q*DD)
// total = 5,510,400 floats = 22.0 MB

// =====================================================================
// K0: all row-parallel precompute as ONE register-tile GEMM + row stage.
// (unchanged — off the critical top-5 since round 5)
// =====================================================================
__global__ __launch_bounds__(256) void k0_kernel(
    const int* __restrict__ qd, const int* __restrict__ qadx,
    const int* __restrict__ ld,
    const float* __restrict__ Kmat, const float* __restrict__ qemb,
    const float* __restrict__ qaemb,
    const float* __restrict__ We, const float* __restrict__ Wa,
    const float* __restrict__ be, const float* __restrict__ ba,
    float* __restrict__ eaW, float* __restrict__ wrecW,
    float* __restrict__ Pzero,          // Pq base; Pq+Pl contiguous
    float* __restrict__ q_e_o, float* __restrict__ le_last)
{
    __shared__ float smem[16384];       // 64 KB: [X 16K | W 48K -> Out 48K]
    float* sX   = smem;                 // [64][64]
    float* sW   = smem + 4096;          // [16][192][4] k4-interleaved
    float* sOut = smem + 4096;          // aliases sW after the k-loop: [64][192]

    int tid = threadIdx.x;
    int bid = blockIdx.x;

    // zero the phaseA atomic accumulators (Pq,Pl contiguous)
    for (int i = bid*256 + tid; i < 2*NROWS_Q*DD; i += NGB*256) Pzero[i] = 0.f;

    int bt, base;
    if (bid < NBLK_L)              { bt = 0; base = bid*RB; }
    else if (bid < NBLK_L+NBLK_Q)  { bt = 1; base = (bid-NBLK_L)*RB; }
    else                           { bt = 2; base = (bid-NBLK_L-NBLK_Q)*RB; }

    // ---- stage X tile (embedding gather) ----
    {
        const int*   idsrc = (bt==0) ? ld : (bt==1) ? qd : qadx;
        const float* tab   = (bt==2) ? qaemb : qemb;
        for (int idx = tid; idx < RB*16; idx += 256) {
            int r = idx >> 4, q = idx & 15;
            int id = idsrc[base + r];
            *(float4*)(sX + r*64 + q*4) =
                *(const float4*)(tab + (size_t)id*DD + q*4);
        }
    }
    // ---- stage Wcat (k4-interleaved) ----
    for (int i = tid; i < 12288; i += 256) {
        int k4 = i / 768, rem = i - k4*768;
        int c = rem >> 2, j = rem & 3;
        int k = k4*4 + j;
        float v;
        if      (c < 64)  v = We[k*64 + c];
        else if (c < 128) v = Wa[k*64 + (c-64)];
        else if (c < 178) v = Kmat[(c-128)*64 + k];
        else              v = 0.f;
        sW[i] = v;
    }
    __syncthreads();

    // ---- GEMM: out[r][c] = sum_k X[r][k]*Wcat[k][c] ----
    int rg = tid >> 5, cg = tid & 31;
    int r0 = rg*8, c0 = cg*6;
    float acc[8][6];
    #pragma unroll
    for (int i = 0; i < 8; ++i)
        #pragma unroll
        for (int c = 0; c < 6; ++c) acc[i][c] = 0.f;

    #pragma unroll 2
    for (int k4 = 0; k4 < 16; ++k4) {
        float4 xv[8], wv[6];
        #pragma unroll
        for (int i = 0; i < 8; ++i)
            xv[i] = *(const float4*)(sX + (r0+i)*64 + k4*4);
        #pragma unroll
        for (int c = 0; c < 6; ++c)
            wv[c] = *(const float4*)(sW + k4*768 + (c0+c)*4);
        #pragma unroll
        for (int i = 0; i < 8; ++i)
            #pragma unroll
            for (int c = 0; c < 6; ++c) {
                acc[i][c] = fmaf(xv[i].x, wv[c].x, acc[i][c]);
                acc[i][c] = fmaf(xv[i].y, wv[c].y, acc[i][c]);
                acc[i][c] = fmaf(xv[i].z, wv[c].z, acc[i][c]);
                acc[i][c] = fmaf(xv[i].w, wv[c].w, acc[i][c]);
            }
    }
    __syncthreads();            // all waves done reading sW
    #pragma unroll
    for (int i = 0; i < 8; ++i)
        #pragma unroll
        for (int c = 0; c < 6; ++c)
            sOut[(r0+i)*192 + c0 + c] = acc[i][c];
    __syncthreads();

    // ---- stage 2: per-row nonlinearity + packing; wave per row ----
    int lane = tid & 63, wvi = tid >> 6;
    float bev = be[lane], bav = ba[lane];

    auto rowsoftmax = [&](const float* orow) -> float {
        float sc = orow[128 + lane];
        float s = (lane < CC) ? sc : -1e30f;
        float mx = s;
        #pragma unroll
        for (int o = 32; o >= 1; o >>= 1) mx = fmaxf(mx, __shfl_xor(mx, o));
        float p = (lane < CC) ? expf(s - mx) : 0.f;
        float sum = p;
        #pragma unroll
        for (int o = 32; o >= 1; o >>= 1) sum += __shfl_xor(sum, o);
        return p / sum;
    };

    for (int i = 0; i < 16; ++i) {
        int rr = wvi*16 + i;
        int grow = base + rr;
        const float* orow = sOut + rr*192;

        if (bt == 0) {
            float erv = 1.f / (1.f + expf(-(orow[lane] + bev)));
            float adv = tanhf(orow[64 + lane] + bav);
            float wsm = rowsoftmax(orow);
            int bs = grow >> 4, il = grow & 15;
            *(float2*)(eaW + (size_t)bs*EA_ST + il*128 + lane*2) =
                make_float2(erv, adv);
            int b = bs / SS, s2 = bs - b*SS;
            if (lane < 52) {
                int omx = lane >> 2, j = lane & 3;
                wrecW[(((size_t)(b*NCH + omx)*SS + s2)*17 + il)*4 + j] =
                    (lane < CC) ? wsm : 0.f;
            }
            if (il == LL-1) le_last[(size_t)bs*DD + lane] = sX[rr*64 + lane];
        } else if (bt == 1) {
            float wsm = rowsoftmax(orow);
            int qrow = grow;
            int b = qrow / SS, s2 = qrow - b*SS;
            if (lane < 52) {
                int omx = lane >> 2, j = lane & 3;
                wrecW[(((size_t)(b*NCH + omx)*SS + s2)*17 + 16)*4 + j] =
                    (lane < CC) ? wsm : 0.f;
            }
            q_e_o[(size_t)qrow*DD + lane] = sX[rr*64 + lane];
        } else {
            float erv = 1.f / (1.f + expf(-(orow[lane] + bev)));
            float adv = tanhf(orow[64 + lane] + bav);
            int qrow = grow;
            *(float2*)(eaW + (size_t)qrow*EA_ST + 2048 + lane*2) =
                make_float2(erv, adv);
        }
    }
}

// =====================================================================
// Phase A: sequential scan (unchanged from round 4).
// =====================================================================
__global__ __launch_bounds__(64) void phaseA_kernel(
    const float* __restrict__ M0,
    const float* __restrict__ ea, const float* __restrict__ wrec,
    float* __restrict__ Pq, float* __restrict__ Pl)
{
    int om   = blockIdx.x >> 5;     // 0..12
    int b    = blockIdx.x & 31;     // 0..31
    int lane = threadIdx.x;
    int c0   = om * 4;

    __shared__ __align__(16) float wbuf[2][W_ST];

    float M[4];
    #pragma unroll
    for (int i = 0; i < 4; ++i) {
        int c = c0 + i;
        M[i] = (c < CC) ? M0[c*DD + lane] : 0.f;
    }

    const float* eb = ea   + (size_t)b*SS*EA_ST + lane*2;
    const float* wb = wrec + (size_t)(b*NCH + om)*SS*W_ST;
    float* pq = Pq + (size_t)b*SS*DD + lane;
    float* pl = Pl + (size_t)b*SS*DD + lane;

    float2 ea0[17], ea1[17];

    // prologue: load step 0 (ea -> regs, w -> wbuf[0])
    #pragma unroll
    for (int il = 0; il < 17; ++il)
        ea0[il] = *(const float2*)(eb + il*128);
    if (lane < 17)
        *(float4*)&wbuf[0][lane*4] = *(const float4*)(wb + lane*4);

    auto step = [&](int s, float2 (&cur)[17], float2 (&nxt)[17], int wbsel) {
        bool pf = (s < SS-1);
        float4 rw;
        if (pf) {
            const float* eg = eb + (size_t)(s+1)*EA_ST;
            #pragma unroll
            for (int il = 0; il < 17; ++il)
                nxt[il] = *(const float2*)(eg + il*128);
            if (lane < 17)
                rw = *(const float4*)(wb + (size_t)(s+1)*W_ST + lane*4);
        }

        // ---- compute step s ----
        float4 qw = *(const float4*)&wbuf[wbsel][64];   // q-chunk w (slot 16)
        float qr;
        qr = qw.x * M[0];
        qr = fmaf(qw.y, M[1], qr);
        qr = fmaf(qw.z, M[2], qr);
        qr = fmaf(qw.w, M[3], qr);

        float a0 = 0.f, a1 = 0.f, a2 = 0.f, a3 = 0.f;
        #pragma unroll
        for (int il = 0; il < 16; ++il) {
            float4 w = *(const float4*)&wbuf[wbsel][il*4];
            float e = cur[il].x, a = cur[il].y;
            a0 = fmaf(w.x, M[0], a0);
            a1 = fmaf(w.y, M[1], a1);
            a2 = fmaf(w.z, M[2], a2);
            a3 = fmaf(w.w, M[3], a3);
            M[0] = fmaf(w.x, fmaf(-e, M[0], a), M[0]);
            M[1] = fmaf(w.y, fmaf(-e, M[1], a), M[1]);
            M[2] = fmaf(w.z, fmaf(-e, M[2], a), M[2]);
            M[3] = fmaf(w.w, fmaf(-e, M[3], a), M[3]);
        }

        atomicAdd(pq + (size_t)s*DD, qr);
        atomicAdd(pl + (size_t)s*DD, (a0 + a1) + (a2 + a3));

        { // final q-write
            float e = cur[16].x, a = cur[16].y;
            M[0] = fmaf(qw.x, fmaf(-e, M[0], a), M[0]);
            M[1] = fmaf(qw.y, fmaf(-e, M[1], a), M[1]);
            M[2] = fmaf(qw.z, fmaf(-e, M[2], a), M[2]);
            M[3] = fmaf(qw.w, fmaf(-e, M[3], a), M[3]);
        }

        // write next w-record late (vmcnt wait lands after compute)
        if (pf && lane < 17)
            *(float4*)&wbuf[wbsel ^ 1][lane*4] = rw;
    };

    for (int s = 0; s < SS; s += 2) {
        step(s,     ea0, ea1, 0);
        step(s + 1, ea1, ea0, 1);
    }
}

// =====================================================================
// Phase B v3.1: mastery -> LN -> MLP -> sigmoid -> out.
// 8 rows per 256-thread block, 200 blocks. Thread j owns output col j.
// W streaming: register double-buffered batches of KBAT=16 column loads
// (wA/wB, statically indexed, NO barriers in the k-loop, nothing held
// across __syncthreads). v3 BUG FIXED: loop now covers all NBAT=16
// batches (k = 0..255), not 8.
// =====================================================================
__global__ __launch_bounds__(256) void phaseB_kernel(
    const float* __restrict__ Pq, const float* __restrict__ Pl,
    const float* __restrict__ q_e_i, const float* __restrict__ le_last,
    const float* __restrict__ ln_g, const float* __restrict__ ln_b,
    const float* __restrict__ W0, const float* __restrict__ b0,
    const float* __restrict__ W1, const float* __restrict__ b1,
    const float* __restrict__ Wout, const float* __restrict__ bout,
    float* __restrict__ out)
{
    __shared__ float m[8][H4];          // 8 KB
    __shared__ float h[8][H4];          // 8 KB
    __shared__ float red[8][4];

    int j = threadIdx.x;                // owns output column j
    int g0 = blockIdx.x * 8;
    int lane = j & 63, wv = j >> 6;

    // ---- build mastery = [q_read | q_e | l_read | le_last] ----
    int seg = j >> 6, dd = j & 63;
    #pragma unroll
    for (int r = 0; r < 8; ++r) {
        int g = g0 + r;
        float v;
        if      (seg == 0) v = Pq[(size_t)g*DD + dd];
        else if (seg == 1) v = q_e_i[(size_t)g*DD + dd];
        else if (seg == 2) v = Pl[(size_t)g*DD + dd];
        else               v = le_last[(size_t)g*DD + dd];
        m[r][j] = v;
    }
    __syncthreads();

    // ---- LayerNorm: wave wv normalizes rows wv and wv+4 ----
    #pragma unroll
    for (int rr = 0; rr < 2; ++rr) {
        int r = wv + rr*4;
        float4 v4 = *(((const float4*)&m[r][0]) + lane);
        float s1 = v4.x + v4.y + v4.z + v4.w;
        float s2 = v4.x*v4.x + v4.y*v4.y + v4.z*v4.z + v4.w*v4.w;
        #pragma unroll
        for (int o = 32; o >= 1; o >>= 1) {
            s1 += __shfl_xor(s1, o);
            s2 += __shfl_xor(s2, o);
        }
        float mu  = s1 * (1.f/256.f);
        float var = s2 * (1.f/256.f) - mu*mu;
        float is  = rsqrtf(var + 1e-5f);
        float4 g4 = *(((const float4*)ln_g) + lane);
        float4 b4 = *(((const float4*)ln_b) + lane);
        float4 o4;
        o4.x = (v4.x - mu)*is*g4.x + b4.x;
        o4.y = (v4.y - mu)*is*g4.y + b4.y;
        o4.z = (v4.z - mu)*is*g4.z + b4.z;
        o4.w = (v4.w - mu)*is*g4.w + b4.w;
        *(((float4*)&m[r][0]) + lane) = o4;
    }
    __syncthreads();

    // ---- GEMM1: acc = m @ W0 + b0 (NBAT=16 batches of KBAT=16 k) ----
    const float* Wp = W0 + j;
    float acc[8];
    {
        float bj = b0[j];
        #pragma unroll
        for (int r = 0; r < 8; ++r) acc[r] = bj;
    }
    {
        float wA[KBAT], wB[KBAT];
        #pragma unroll
        for (int t = 0; t < KBAT; ++t) wA[t] = Wp[(size_t)t*H4];
        #pragma unroll 1
        for (int kb = 0; kb < NBAT; kb += 2) {
            // prefetch batch kb+1
            #pragma unroll
            for (int t = 0; t < KBAT; ++t)
                wB[t] = Wp[(size_t)((kb+1)*KBAT + t)*H4];
            // compute batch kb from wA
            #pragma unroll
            for (int t4 = 0; t4 < KBAT/4; ++t4) {
                #pragma unroll
                for (int r = 0; r < 8; ++r) {
                    float4 mv = *(const float4*)&m[r][kb*KBAT + t4*4];
                    acc[r] = fmaf(mv.x, wA[t4*4+0], acc[r]);
                    acc[r] = fmaf(mv.y, wA[t4*4+1], acc[r]);
                    acc[r] = fmaf(mv.z, wA[t4*4+2], acc[r]);
                    acc[r] = fmaf(mv.w, wA[t4*4+3], acc[r]);
                }
            }
            // prefetch batch kb+2 (uniform branch)
            if (kb + 2 < NBAT) {
                #pragma unroll
                for (int t = 0; t < KBAT; ++t)
                    wA[t] = Wp[(size_t)((kb+2)*KBAT + t)*H4];
            }
            // compute batch kb+1 from wB
            #pragma unroll
            for (int t4 = 0; t4 < KBAT/4; ++t4) {
                #pragma unroll
                for (int r = 0; r < 8; ++r) {
                    float4 mv = *(const float4*)&m[r][(kb+1)*KBAT + t4*4];
                    acc[r] = fmaf(mv.x, wB[t4*4+0], acc[r]);
                    acc[r] = fmaf(mv.y, wB[t4*4+1], acc[r]);
                    acc[r] = fmaf(mv.z, wB[t4*4+2], acc[r]);
                    acc[r] = fmaf(mv.w, wB[t4*4+3], acc[r]);
                }
            }
        }
    }
    #pragma unroll
    for (int r = 0; r < 8; ++r) h[r][j] = fmaxf(acc[r], 0.f);
    __syncthreads();

    // ---- GEMM2: a2 = h @ W1 + b1 (same schedule) ----
    const float* Wp1 = W1 + j;
    float a2[8];
    {
        float bj = b1[j];
        #pragma unroll
        for (int r = 0; r < 8; ++r) a2[r] = bj;
    }
    {
        float wA[KBAT], wB[KBAT];
        #pragma unroll
        for (int t = 0; t < KBAT; ++t) wA[t] = Wp1[(size_t)t*H4];
        #pragma unroll 1
        for (int kb = 0; kb < NBAT; kb += 2) {
            #pragma unroll
            for (int t = 0; t < KBAT; ++t)
                wB[t] = Wp1[(size_t)((kb+1)*KBAT + t)*H4];
            #pragma unroll
            for (int t4 = 0; t4 < KBAT/4; ++t4) {
                #pragma unroll
                for (int r = 0; r < 8; ++r) {
                    float4 hv = *(const float4*)&h[r][kb*KBAT + t4*4];
                    a2[r] = fmaf(hv.x, wA[t4*4+0], a2[r]);
                    a2[r] = fmaf(hv.y, wA[t4*4+1], a2[r]);
                    a2[r] = fmaf(hv.z, wA[t4*4+2], a2[r]);
                    a2[r] = fmaf(hv.w, wA[t4*4+3], a2[r]);
                }
            }
            if (kb + 2 < NBAT) {
                #pragma unroll
                for (int t = 0; t < KBAT; ++t)
                    wA[t] = Wp1[(size_t)((kb+2)*KBAT + t)*H4];
            }
            #pragma unroll
            for (int t4 = 0; t4 < KBAT/4; ++t4) {
                #pragma unroll
                for (int r = 0; r < 8; ++r) {
                    float4 hv = *(const float4*)&h[r][(kb+1)*KBAT + t4*4];
                    a2[r] = fmaf(hv.x, wB[t4*4+0], a2[r]);
                    a2[r] = fmaf(hv.y, wB[t4*4+1], a2[r]);
                    a2[r] = fmaf(hv.z, wB[t4*4+2], a2[r]);
                    a2[r] = fmaf(hv.w, wB[t4*4+3], a2[r]);
                }
            }
        }
    }

    // ---- pred = sigmoid(h1 . Wout + bout) ----
    float wo = Wout[j];
    #pragma unroll
    for (int r = 0; r < 8; ++r) {
        float v = a2[r] * wo;
        #pragma unroll
        for (int o = 32; o >= 1; o >>= 1) v += __shfl_xor(v, o);
        if (lane == 0) red[r][wv] = v;
    }
    __syncthreads();
    if (j < 8) {
        float t = red[j][0] + red[j][1] + red[j][2] + red[j][3] + bout[0];
        out[g0 + j] = 1.f / (1.f + expf(-t));
    }
}

// =====================================================================
extern "C" void kernel_launch(void* const* d_in, const int* in_sizes, int n_in,
                              void* d_out, int out_size, void* d_ws, size_t ws_size,
                              hipStream_t stream)
{
    const int*   q_data  = (const int*)  d_in[0];
    const int*   qa_data = (const int*)  d_in[1];
    const int*   l_data  = (const int*)  d_in[2];
    // d_in[3] users: unused by reference forward
    const float* Kmat    = (const float*)d_in[4];
    const float* q_embed = (const float*)d_in[5];
    const float* qa_embed= (const float*)d_in[6];
    // d_in[7] u_embed: unused by reference forward
    const float* M0      = (const float*)d_in[8];
    const float* W_e     = (const float*)d_in[9];
    const float* b_e     = (const float*)d_in[10];
    const float* W_a     = (const float*)d_in[11];
    const float* b_a     = (const float*)d_in[12];
    const float* ln_g    = (const float*)d_in[13];
    const float* ln_b    = (const float*)d_in[14];
    const float* W0      = (const float*)d_in[15];
    const float* b0      = (const float*)d_in[16];
    const float* W1      = (const float*)d_in[17];
    const float* b1      = (const float*)d_in[18];
    const float* W_out   = (const float*)d_in[19];
    const float* b_out   = (const float*)d_in[20];

    float* ws = (float*)d_ws;
    float* eaW     = ws + OFF_EA;
    float* wrecW   = ws + OFF_W;
    float* Pq      = ws + OFF_PQ;
    float* Pl      = ws + OFF_PL;
    float* q_e     = ws + OFF_QE;
    float* le_last = ws + OFF_LELAST;

    float* out = (float*)d_out;

    k0_kernel<<<NGB, 256, 0, stream>>>(q_data, qa_data, l_data,
                                       Kmat, q_embed, qa_embed,
                                       W_e, W_a, b_e, b_a,
                                       eaW, wrecW, Pq,
                                       q_e, le_last);
    phaseA_kernel<<<BB*NCH, 64, 0, stream>>>(M0, eaW, wrecW, Pq, Pl);
    phaseB_kernel<<<NROWS_Q/8, 256, 0, stream>>>(Pq, Pl, q_e, le_last,
                                                 ln_g, ln_b, W0, b0, W1, b1,
                                                 W_out, b_out, out);
}

// Round 9
// 206.590 us; speedup vs baseline: 1.2667x; 1.0253x over previous
//
#include <hip/hip_runtime.h>
#include <math.h>

// Problem constants
#define BB 32
#define SS 50
#define LL 16
#define CC 50
#define DD 64
#define NCH 13           // c-chunks of 4 rows (C=50 padded to 52)
#define H4 256
#define NROWS_Q (BB*SS)            // 1600
#define NROWS_L (BB*SS*LL)         // 25600

#define EA_ST 2304       // floats per (b,s) ea record: 17 slots * 128, padded
#define W_ST  68         // floats per (b,om,s) w record: 17 * 4

// GEMM geometry for k0
#define RB 64                       // rows per block
#define NBLK_L (NROWS_L/RB)         // 400
#define NBLK_Q (NROWS_Q/RB)         // 25
#define NGB (NBLK_L + 2*NBLK_Q)     // 450

// phaseB k-batching: 16 k-rows per register batch
#define KBAT 16
#define NBAT (H4/KBAT)              // 16 batches — MUST cover all of H4

// Layout invariants shared by k0 (producer) and phaseA (consumer)
static_assert(EA_ST == 17*128 + 128, "ea record: 17 slots x 64 lanes x float2, +pad");
static_assert(W_ST == 17*4, "w record: 17 slots x 4 chunk-cols");
static_assert(SS % 2 == 0, "phaseA double-step pipeline needs even SS");
static_assert(NROWS_L % RB == 0 && NROWS_Q % RB == 0, "GEMM row blocking");
static_assert(NBAT*KBAT == H4 && NBAT % 2 == 0,
              "phaseB k-loop must cover ALL of H4 in pairs of batches");

// ---------------- workspace layout (floats) ----------------
#define OFF_EA     ((size_t)0)
#define OFF_W      (OFF_EA + (size_t)NROWS_Q*EA_ST)
#define OFF_PQ     (OFF_W  + (size_t)BB*NCH*SS*W_ST)
#define OFF_PL     (OFF_PQ + (size_t)NROWS_Q*DD)
#define OFF_QE     (OFF_PL + (size_t)NROWS_Q*DD)
#define OFF_LELAST (OFF_QE + (size_t)NROWS_Q*DD)
// total = 5,510,400 floats = 22.0 MB

// =====================================================================
// K0 v2: row-parallel precompute GEMM with REGISTER-resident output.
// Wave owns 16 complete rows; lane owns output cols {lane,64+lane,128+lane}
// = exactly the (er, ad, softmax-score) triple stage-2 needs per lane.
// No sOut staging, no output barriers. sW staged k-major [32][192] in two
// k-chunks (24 KB); reads are stride-4B conflict-free b32; sX reads are
// wave-uniform b128 broadcasts. LDS 40 KB -> 4 blocks/CU.
// =====================================================================
__global__ __launch_bounds__(256, 4) void k0_kernel(
    const int* __restrict__ qd, const int* __restrict__ qadx,
    const int* __restrict__ ld,
    const float* __restrict__ Kmat, const float* __restrict__ qemb,
    const float* __restrict__ qaemb,
    const float* __restrict__ We, const float* __restrict__ Wa,
    const float* __restrict__ be, const float* __restrict__ ba,
    float* __restrict__ eaW, float* __restrict__ wrecW,
    float* __restrict__ Pzero,          // Pq base; Pq+Pl contiguous
    float* __restrict__ q_e_o, float* __restrict__ le_last)
{
    __shared__ float sX[RB*DD];         // 16 KB  [64 rows][64 k]
    __shared__ float sW[32*192];        // 24 KB  [32 k][192 cols], 2 chunks

    int tid = threadIdx.x;
    int bid = blockIdx.x;

    // zero the phaseA atomic accumulators (Pq,Pl contiguous)
    for (int i = bid*256 + tid; i < 2*NROWS_Q*DD; i += NGB*256) Pzero[i] = 0.f;

    int bt, base;
    if (bid < NBLK_L)              { bt = 0; base = bid*RB; }
    else if (bid < NBLK_L+NBLK_Q)  { bt = 1; base = (bid-NBLK_L)*RB; }
    else                           { bt = 2; base = (bid-NBLK_L-NBLK_Q)*RB; }

    // ---- stage X tile (embedding gather, coalesced float4) ----
    {
        const int*   idsrc = (bt==0) ? ld : (bt==1) ? qd : qadx;
        const float* tab   = (bt==2) ? qaemb : qemb;
        for (int idx = tid; idx < RB*16; idx += 256) {
            int r = idx >> 4, q = idx & 15;
            int id = idsrc[base + r];
            *(float4*)(sX + r*64 + q*4) =
                *(const float4*)(tab + (size_t)id*DD + q*4);
        }
    }

    // W chunk staging: k-rows [kb, kb+32) of Wcat[64][192] = [W_e|W_a|K^T]
    auto stageW = [&](int kb) {
        // cols [0,128): 1024 float4s, coalesced from We/Wa
        #pragma unroll
        for (int n = 0; n < 4; ++n) {
            int f  = n*256 + tid;
            int kl = f >> 5, cf = f & 31;
            int k  = kb + kl;
            const float* src = (cf < 16) ? (We + k*64 + cf*4)
                                         : (Wa + k*64 + (cf-16)*4);
            *(float4*)(sW + kl*192 + cf*4) = *(const float4*)src;
        }
        // cols [128,192): K^T (scattered scalar, small), pad c>=50 with 0
        #pragma unroll
        for (int n = 0; n < 8; ++n) {
            int f  = n*256 + tid;
            int kl = f >> 6, cr = f & 63;
            int k  = kb + kl;
            sW[kl*192 + 128 + cr] = (cr < CC) ? Kmat[cr*64 + k] : 0.f;
        }
    };

    int lane = tid & 63, wvi = tid >> 6;
    int r0 = wvi * 16;

    float accE[16], accA[16], accS[16];
    #pragma unroll
    for (int r = 0; r < 16; ++r) { accE[r] = 0.f; accA[r] = 0.f; accS[r] = 0.f; }

    stageW(0);
    __syncthreads();

    // ---- GEMM chunk 0: k in [0,32) ----
    #pragma unroll 2
    for (int k4 = 0; k4 < 8; ++k4) {
        float wE[4], wA4[4], wS[4];
        #pragma unroll
        for (int kk = 0; kk < 4; ++kk) {
            int krow = (k4*4 + kk)*192;
            wE[kk]  = sW[krow + lane];
            wA4[kk] = sW[krow + 64 + lane];
            wS[kk]  = sW[krow + 128 + lane];
        }
        #pragma unroll
        for (int r = 0; r < 16; ++r) {
            float4 xv = *(const float4*)(sX + (r0+r)*64 + k4*4);
            accE[r] = fmaf(xv.x, wE[0], accE[r]);
            accE[r] = fmaf(xv.y, wE[1], accE[r]);
            accE[r] = fmaf(xv.z, wE[2], accE[r]);
            accE[r] = fmaf(xv.w, wE[3], accE[r]);
            accA[r] = fmaf(xv.x, wA4[0], accA[r]);
            accA[r] = fmaf(xv.y, wA4[1], accA[r]);
            accA[r] = fmaf(xv.z, wA4[2], accA[r]);
            accA[r] = fmaf(xv.w, wA4[3], accA[r]);
            accS[r] = fmaf(xv.x, wS[0], accS[r]);
            accS[r] = fmaf(xv.y, wS[1], accS[r]);
            accS[r] = fmaf(xv.z, wS[2], accS[r]);
            accS[r] = fmaf(xv.w, wS[3], accS[r]);
        }
    }
    __syncthreads();            // done reading sW chunk 0

    stageW(32);
    __syncthreads();

    // ---- GEMM chunk 1: k in [32,64) ----
    #pragma unroll 2
    for (int k4 = 0; k4 < 8; ++k4) {
        float wE[4], wA4[4], wS[4];
        #pragma unroll
        for (int kk = 0; kk < 4; ++kk) {
            int krow = (k4*4 + kk)*192;
            wE[kk]  = sW[krow + lane];
            wA4[kk] = sW[krow + 64 + lane];
            wS[kk]  = sW[krow + 128 + lane];
        }
        #pragma unroll
        for (int r = 0; r < 16; ++r) {
            float4 xv = *(const float4*)(sX + (r0+r)*64 + 32 + k4*4);
            accE[r] = fmaf(xv.x, wE[0], accE[r]);
            accE[r] = fmaf(xv.y, wE[1], accE[r]);
            accE[r] = fmaf(xv.z, wE[2], accE[r]);
            accE[r] = fmaf(xv.w, wE[3], accE[r]);
            accA[r] = fmaf(xv.x, wA4[0], accA[r]);
            accA[r] = fmaf(xv.y, wA4[1], accA[r]);
            accA[r] = fmaf(xv.z, wA4[2], accA[r]);
            accA[r] = fmaf(xv.w, wA4[3], accA[r]);
            accS[r] = fmaf(xv.x, wS[0], accS[r]);
            accS[r] = fmaf(xv.y, wS[1], accS[r]);
            accS[r] = fmaf(xv.z, wS[2], accS[r]);
            accS[r] = fmaf(xv.w, wS[3], accS[r]);
        }
    }

    // ---- stage 2: per-row nonlinearity + packing, straight from regs ----
    float bev = be[lane], bav = ba[lane];

    #pragma unroll
    for (int r = 0; r < 16; ++r) {
        int rr = r0 + r;
        int grow = base + rr;

        // softmax over lanes 0..49 of accS[r]
        float s = (lane < CC) ? accS[r] : -1e30f;
        float mx = s;
        #pragma unroll
        for (int o = 32; o >= 1; o >>= 1) mx = fmaxf(mx, __shfl_xor(mx, o));
        float p = (lane < CC) ? expf(s - mx) : 0.f;
        float sum = p;
        #pragma unroll
        for (int o = 32; o >= 1; o >>= 1) sum += __shfl_xor(sum, o);
        float wsm = p / sum;

        if (bt == 0) {
            float erv = 1.f / (1.f + expf(-(accE[r] + bev)));
            float adv = tanhf(accA[r] + bav);
            int bs = grow >> 4, il = grow & 15;
            *(float2*)(eaW + (size_t)bs*EA_ST + il*128 + lane*2) =
                make_float2(erv, adv);
            int b = bs / SS, s2 = bs - b*SS;
            if (lane < 52) {
                int omx = lane >> 2, j = lane & 3;
                wrecW[(((size_t)(b*NCH + omx)*SS + s2)*17 + il)*4 + j] =
                    (lane < CC) ? wsm : 0.f;
            }
            if (il == LL-1) le_last[(size_t)bs*DD + lane] = sX[rr*64 + lane];
        } else if (bt == 1) {
            int qrow = grow;
            int b = qrow / SS, s2 = qrow - b*SS;
            if (lane < 52) {
                int omx = lane >> 2, j = lane & 3;
                wrecW[(((size_t)(b*NCH + omx)*SS + s2)*17 + 16)*4 + j] =
                    (lane < CC) ? wsm : 0.f;
            }
            q_e_o[(size_t)qrow*DD + lane] = sX[rr*64 + lane];
        } else {
            float erv = 1.f / (1.f + expf(-(accE[r] + bev)));
            float adv = tanhf(accA[r] + bav);
            int qrow = grow;
            *(float2*)(eaW + (size_t)qrow*EA_ST + 2048 + lane*2) =
                make_float2(erv, adv);
        }
    }
}

// =====================================================================
// Phase A: sequential scan (unchanged from round 4).
// =====================================================================
__global__ __launch_bounds__(64) void phaseA_kernel(
    const float* __restrict__ M0,
    const float* __restrict__ ea, const float* __restrict__ wrec,
    float* __restrict__ Pq, float* __restrict__ Pl)
{
    int om   = blockIdx.x >> 5;     // 0..12
    int b    = blockIdx.x & 31;     // 0..31
    int lane = threadIdx.x;
    int c0   = om * 4;

    __shared__ __align__(16) float wbuf[2][W_ST];

    float M[4];
    #pragma unroll
    for (int i = 0; i < 4; ++i) {
        int c = c0 + i;
        M[i] = (c < CC) ? M0[c*DD + lane] : 0.f;
    }

    const float* eb = ea   + (size_t)b*SS*EA_ST + lane*2;
    const float* wb = wrec + (size_t)(b*NCH + om)*SS*W_ST;
    float* pq = Pq + (size_t)b*SS*DD + lane;
    float* pl = Pl + (size_t)b*SS*DD + lane;

    float2 ea0[17], ea1[17];

    // prologue: load step 0 (ea -> regs, w -> wbuf[0])
    #pragma unroll
    for (int il = 0; il < 17; ++il)
        ea0[il] = *(const float2*)(eb + il*128);
    if (lane < 17)
        *(float4*)&wbuf[0][lane*4] = *(const float4*)(wb + lane*4);

    auto step = [&](int s, float2 (&cur)[17], float2 (&nxt)[17], int wbsel) {
        bool pf = (s < SS-1);
        float4 rw;
        if (pf) {
            const float* eg = eb + (size_t)(s+1)*EA_ST;
            #pragma unroll
            for (int il = 0; il < 17; ++il)
                nxt[il] = *(const float2*)(eg + il*128);
            if (lane < 17)
                rw = *(const float4*)(wb + (size_t)(s+1)*W_ST + lane*4);
        }

        // ---- compute step s ----
        float4 qw = *(const float4*)&wbuf[wbsel][64];   // q-chunk w (slot 16)
        float qr;
        qr = qw.x * M[0];
        qr = fmaf(qw.y, M[1], qr);
        qr = fmaf(qw.z, M[2], qr);
        qr = fmaf(qw.w, M[3], qr);

        float a0 = 0.f, a1 = 0.f, a2 = 0.f, a3 = 0.f;
        #pragma unroll
        for (int il = 0; il < 16; ++il) {
            float4 w = *(const float4*)&wbuf[wbsel][il*4];
            float e = cur[il].x, a = cur[il].y;
            a0 = fmaf(w.x, M[0], a0);
            a1 = fmaf(w.y, M[1], a1);
            a2 = fmaf(w.z, M[2], a2);
            a3 = fmaf(w.w, M[3], a3);
            M[0] = fmaf(w.x, fmaf(-e, M[0], a), M[0]);
            M[1] = fmaf(w.y, fmaf(-e, M[1], a), M[1]);
            M[2] = fmaf(w.z, fmaf(-e, M[2], a), M[2]);
            M[3] = fmaf(w.w, fmaf(-e, M[3], a), M[3]);
        }

        atomicAdd(pq + (size_t)s*DD, qr);
        atomicAdd(pl + (size_t)s*DD, (a0 + a1) + (a2 + a3));

        { // final q-write
            float e = cur[16].x, a = cur[16].y;
            M[0] = fmaf(qw.x, fmaf(-e, M[0], a), M[0]);
            M[1] = fmaf(qw.y, fmaf(-e, M[1], a), M[1]);
            M[2] = fmaf(qw.z, fmaf(-e, M[2], a), M[2]);
            M[3] = fmaf(qw.w, fmaf(-e, M[3], a), M[3]);
        }

        // write next w-record late (vmcnt wait lands after compute)
        if (pf && lane < 17)
            *(float4*)&wbuf[wbsel ^ 1][lane*4] = rw;
    };

    for (int s = 0; s < SS; s += 2) {
        step(s,     ea0, ea1, 0);
        step(s + 1, ea1, ea0, 1);
    }
}

// =====================================================================
// Phase B v3.1: mastery -> LN -> MLP -> sigmoid -> out.
// (unchanged from round 7 — correctness-fixed register-streamed GEMMs)
// =====================================================================
__global__ __launch_bounds__(256) void phaseB_kernel(
    const float* __restrict__ Pq, const float* __restrict__ Pl,
    const float* __restrict__ q_e_i, const float* __restrict__ le_last,
    const float* __restrict__ ln_g, const float* __restrict__ ln_b,
    const float* __restrict__ W0, const float* __restrict__ b0,
    const float* __restrict__ W1, const float* __restrict__ b1,
    const float* __restrict__ Wout, const float* __restrict__ bout,
    float* __restrict__ out)
{
    __shared__ float m[8][H4];          // 8 KB
    __shared__ float h[8][H4];          // 8 KB
    __shared__ float red[8][4];

    int j = threadIdx.x;                // owns output column j
    int g0 = blockIdx.x * 8;
    int lane = j & 63, wv = j >> 6;

    // ---- build mastery = [q_read | q_e | l_read | le_last] ----
    int seg = j >> 6, dd = j & 63;
    #pragma unroll
    for (int r = 0; r < 8; ++r) {
        int g = g0 + r;
        float v;
        if      (seg == 0) v = Pq[(size_t)g*DD + dd];
        else if (seg == 1) v = q_e_i[(size_t)g*DD + dd];
        else if (seg == 2) v = Pl[(size_t)g*DD + dd];
        else               v = le_last[(size_t)g*DD + dd];
        m[r][j] = v;
    }
    __syncthreads();

    // ---- LayerNorm: wave wv normalizes rows wv and wv+4 ----
    #pragma unroll
    for (int rr = 0; rr < 2; ++rr) {
        int r = wv + rr*4;
        float4 v4 = *(((const float4*)&m[r][0]) + lane);
        float s1 = v4.x + v4.y + v4.z + v4.w;
        float s2 = v4.x*v4.x + v4.y*v4.y + v4.z*v4.z + v4.w*v4.w;
        #pragma unroll
        for (int o = 32; o >= 1; o >>= 1) {
            s1 += __shfl_xor(s1, o);
            s2 += __shfl_xor(s2, o);
        }
        float mu  = s1 * (1.f/256.f);
        float var = s2 * (1.f/256.f) - mu*mu;
        float is  = rsqrtf(var + 1e-5f);
        float4 g4 = *(((const float4*)ln_g) + lane);
        float4 b4 = *(((const float4*)ln_b) + lane);
        float4 o4;
        o4.x = (v4.x - mu)*is*g4.x + b4.x;
        o4.y = (v4.y - mu)*is*g4.y + b4.y;
        o4.z = (v4.z - mu)*is*g4.z + b4.z;
        o4.w = (v4.w - mu)*is*g4.w + b4.w;
        *(((float4*)&m[r][0]) + lane) = o4;
    }
    __syncthreads();

    // ---- GEMM1: acc = m @ W0 + b0 (NBAT=16 batches of KBAT=16 k) ----
    const float* Wp = W0 + j;
    float acc[8];
    {
        float bj = b0[j];
        #pragma unroll
        for (int r = 0; r < 8; ++r) acc[r] = bj;
    }
    {
        float wA[KBAT], wB[KBAT];
        #pragma unroll
        for (int t = 0; t < KBAT; ++t) wA[t] = Wp[(size_t)t*H4];
        #pragma unroll 1
        for (int kb = 0; kb < NBAT; kb += 2) {
            // prefetch batch kb+1
            #pragma unroll
            for (int t = 0; t < KBAT; ++t)
                wB[t] = Wp[(size_t)((kb+1)*KBAT + t)*H4];
            // compute batch kb from wA
            #pragma unroll
            for (int t4 = 0; t4 < KBAT/4; ++t4) {
                #pragma unroll
                for (int r = 0; r < 8; ++r) {
                    float4 mv = *(const float4*)&m[r][kb*KBAT + t4*4];
                    acc[r] = fmaf(mv.x, wA[t4*4+0], acc[r]);
                    acc[r] = fmaf(mv.y, wA[t4*4+1], acc[r]);
                    acc[r] = fmaf(mv.z, wA[t4*4+2], acc[r]);
                    acc[r] = fmaf(mv.w, wA[t4*4+3], acc[r]);
                }
            }
            // prefetch batch kb+2 (uniform branch)
            if (kb + 2 < NBAT) {
                #pragma unroll
                for (int t = 0; t < KBAT; ++t)
                    wA[t] = Wp[(size_t)((kb+2)*KBAT + t)*H4];
            }
            // compute batch kb+1 from wB
            #pragma unroll
            for (int t4 = 0; t4 < KBAT/4; ++t4) {
                #pragma unroll
                for (int r = 0; r < 8; ++r) {
                    float4 mv = *(const float4*)&m[r][(kb+1)*KBAT + t4*4];
                    acc[r] = fmaf(mv.x, wB[t4*4+0], acc[r]);
                    acc[r] = fmaf(mv.y, wB[t4*4+1], acc[r]);
                    acc[r] = fmaf(mv.z, wB[t4*4+2], acc[r]);
                    acc[r] = fmaf(mv.w, wB[t4*4+3], acc[r]);
                }
            }
        }
    }
    #pragma unroll
    for (int r = 0; r < 8; ++r) h[r][j] = fmaxf(acc[r], 0.f);
    __syncthreads();

    // ---- GEMM2: a2 = h @ W1 + b1 (same schedule) ----
    const float* Wp1 = W1 + j;
    float a2[8];
    {
        float bj = b1[j];
        #pragma unroll
        for (int r = 0; r < 8; ++r) a2[r] = bj;
    }
    {
        float wA[KBAT], wB[KBAT];
        #pragma unroll
        for (int t = 0; t < KBAT; ++t) wA[t] = Wp1[(size_t)t*H4];
        #pragma unroll 1
        for (int kb = 0; kb < NBAT; kb += 2) {
            #pragma unroll
            for (int t = 0; t < KBAT; ++t)
                wB[t] = Wp1[(size_t)((kb+1)*KBAT + t)*H4];
            #pragma unroll
            for (int t4 = 0; t4 < KBAT/4; ++t4) {
                #pragma unroll
                for (int r = 0; r < 8; ++r) {
                    float4 hv = *(const float4*)&h[r][kb*KBAT + t4*4];
                    a2[r] = fmaf(hv.x, wA[t4*4+0], a2[r]);
                    a2[r] = fmaf(hv.y, wA[t4*4+1], a2[r]);
                    a2[r] = fmaf(hv.z, wA[t4*4+2], a2[r]);
                    a2[r] = fmaf(hv.w, wA[t4*4+3], a2[r]);
                }
            }
            if (kb + 2 < NBAT) {
                #pragma unroll
                for (int t = 0; t < KBAT; ++t)
                    wA[t] = Wp1[(size_t)((kb+2)*KBAT + t)*H4];
            }
            #pragma unroll
            for (int t4 = 0; t4 < KBAT/4; ++t4) {
                #pragma unroll
                for (int r = 0; r < 8; ++r) {
                    float4 hv = *(const float4*)&h[r][(kb+1)*KBAT + t4*4];
                    a2[r] = fmaf(hv.x, wB[t4*4+0], a2[r]);
                    a2[r] = fmaf(hv.y, wB[t4*4+1], a2[r]);
                    a2[r] = fmaf(hv.z, wB[t4*4+2], a2[r]);
                    a2[r] = fmaf(hv.w, wB[t4*4+3], a2[r]);
                }
            }
        }
    }

    // ---- pred = sigmoid(h1 . Wout + bout) ----
    float wo = Wout[j];
    #pragma unroll
    for (int r = 0; r < 8; ++r) {
        float v = a2[r] * wo;
        #pragma unroll
        for (int o = 32; o >= 1; o >>= 1) v += __shfl_xor(v, o);
        if (lane == 0) red[r][wv] = v;
    }
    __syncthreads();
    if (j < 8) {
        float t = red[j][0] + red[j][1] + red[j][2] + red[j][3] + bout[0];
        out[g0 + j] = 1.f / (1.f + expf(-t));
    }
}

// =====================================================================
extern "C" void kernel_launch(void* const* d_in, const int* in_sizes, int n_in,
                              void* d_out, int out_size, void* d_ws, size_t ws_size,
                              hipStream_t stream)
{
    const int*   q_data  = (const int*)  d_in[0];
    const int*   qa_data = (const int*)  d_in[1];
    const int*   l_data  = (const int*)  d_in[2];
    // d_in[3] users: unused by reference forward
    const float* Kmat    = (const float*)d_in[4];
    const float* q_embed = (const float*)d_in[5];
    const float* qa_embed= (const float*)d_in[6];
    // d_in[7] u_embed: unused by reference forward
    const float* M0      = (const float*)d_in[8];
    const float* W_e     = (const float*)d_in[9];
    const float* b_e     = (const float*)d_in[10];
    const float* W_a     = (const float*)d_in[11];
    const float* b_a     = (const float*)d_in[12];
    const float* ln_g    = (const float*)d_in[13];
    const float* ln_b    = (const float*)d_in[14];
    const float* W0      = (const float*)d_in[15];
    const float* b0      = (const float*)d_in[16];
    const float* W1      = (const float*)d_in[17];
    const float* b1      = (const float*)d_in[18];
    const float* W_out   = (const float*)d_in[19];
    const float* b_out   = (const float*)d_in[20];

    float* ws = (float*)d_ws;
    float* eaW     = ws + OFF_EA;
    float* wrecW   = ws + OFF_W;
    float* Pq      = ws + OFF_PQ;
    float* Pl      = ws + OFF_PL;
    float* q_e     = ws + OFF_QE;
    float* le_last = ws + OFF_LELAST;

    float* out = (float*)d_out;

    k0_kernel<<<NGB, 256, 0, stream>>>(q_data, qa_data, l_data,
                                       Kmat, q_embed, qa_embed,
                                       W_e, W_a, b_e, b_a,
                                       eaW, wrecW, Pq,
                                       q_e, le_last);
    phaseA_kernel<<<BB*NCH, 64, 0, stream>>>(M0, eaW, wrecW, Pq, Pl);
    phaseB_kernel<<<NROWS_Q/8, 256, 0, stream>>>(Pq, Pl, q_e, le_last,
                                                 ln_g, ln_b, W0, b0, W1, b1,
                                                 W_out, b_out, out);
}

// Round 10
// 199.433 us; speedup vs baseline: 1.3122x; 1.0359x over previous
//
#include <hip/hip_runtime.h>
#include <math.h>

// Problem constants
#define BB 32
#define SS 50
#define LL 16
#define CC 50
#define DD 64
#define NCH 13           // c-chunks of 4 rows (C=50 padded to 52)
#define H4 256
#define NROWS_Q (BB*SS)            // 1600
#define NROWS_L (BB*SS*LL)         // 25600

#define EA_ST 2176       // floats per (b,s) ea record: 17 slots * 128
#define W_ST  68         // floats per (b,om,s) w record: 17 * 4

// GEMM geometry for k0
#define RB 64                       // rows per block
#define NBLK_L (NROWS_L/RB)         // 400
#define NBLK_Q (NROWS_Q/RB)         // 25
#define NGB (NBLK_L + 2*NBLK_Q)     // 450

// phaseB k-batching: 16 k-rows per register batch
#define KBAT 16
#define NBAT (H4/KBAT)              // 16 batches — MUST cover all of H4

// Layout invariants shared by k0 (producer) and phaseA (consumer)
static_assert(EA_ST == 17*128, "ea record: 17 slots x 64 lanes x float2");
static_assert(W_ST == 17*4, "w record: 17 slots x 4 chunk-cols");
static_assert(SS % 2 == 0, "phaseA double-step pipeline needs even SS");
static_assert(NROWS_L % RB == 0 && NROWS_Q % RB == 0, "GEMM row blocking");
static_assert(NBAT*KBAT == H4 && NBAT % 2 == 0,
              "phaseB k-loop must cover ALL of H4 in pairs of batches");
static_assert(SS*DD % 4 == 0, "phaseA partial copy uses float4");

// ---------------- workspace layout (floats) ----------------
#define OFF_EA     ((size_t)0)
#define OFF_W      (OFF_EA + (size_t)NROWS_Q*EA_ST)            // +3,481,600
#define OFF_PQP    (OFF_W  + (size_t)BB*NCH*SS*W_ST)           // +1,414,400
#define OFF_PLP    (OFF_PQP + (size_t)NCH*BB*SS*DD)            // +1,331,200
#define OFF_QE     (OFF_PLP + (size_t)NCH*BB*SS*DD)            // +1,331,200
#define OFF_LELAST (OFF_QE + (size_t)NROWS_Q*DD)               // +102,400
// total = 7,763,200 floats = 29.6 MB (same size as the proven round-2 layout)

// =====================================================================
// K0 v2: row-parallel precompute GEMM with REGISTER-resident output.
// Wave owns 16 complete rows; lane owns output cols {lane,64+lane,128+lane}
// = exactly the (er, ad, softmax-score) triple stage-2 needs per lane.
// No sOut staging, no output barriers. sW staged k-major [32][192] in two
// k-chunks (24 KB); conflict-free b32 reads; sX reads wave-uniform b128.
// (Pq zeroing dropped — phaseA now writes full partials, no atomics.)
// =====================================================================
__global__ __launch_bounds__(256, 4) void k0_kernel(
    const int* __restrict__ qd, const int* __restrict__ qadx,
    const int* __restrict__ ld,
    const float* __restrict__ Kmat, const float* __restrict__ qemb,
    const float* __restrict__ qaemb,
    const float* __restrict__ We, const float* __restrict__ Wa,
    const float* __restrict__ be, const float* __restrict__ ba,
    float* __restrict__ eaW, float* __restrict__ wrecW,
    float* __restrict__ q_e_o, float* __restrict__ le_last)
{
    __shared__ float sX[RB*DD];         // 16 KB  [64 rows][64 k]
    __shared__ float sW[32*192];        // 24 KB  [32 k][192 cols], 2 chunks

    int tid = threadIdx.x;
    int bid = blockIdx.x;

    int bt, base;
    if (bid < NBLK_L)              { bt = 0; base = bid*RB; }
    else if (bid < NBLK_L+NBLK_Q)  { bt = 1; base = (bid-NBLK_L)*RB; }
    else                           { bt = 2; base = (bid-NBLK_L-NBLK_Q)*RB; }

    // ---- stage X tile (embedding gather, coalesced float4) ----
    {
        const int*   idsrc = (bt==0) ? ld : (bt==1) ? qd : qadx;
        const float* tab   = (bt==2) ? qaemb : qemb;
        for (int idx = tid; idx < RB*16; idx += 256) {
            int r = idx >> 4, q = idx & 15;
            int id = idsrc[base + r];
            *(float4*)(sX + r*64 + q*4) =
                *(const float4*)(tab + (size_t)id*DD + q*4);
        }
    }

    // W chunk staging: k-rows [kb, kb+32) of Wcat[64][192] = [W_e|W_a|K^T]
    auto stageW = [&](int kb) {
        #pragma unroll
        for (int n = 0; n < 4; ++n) {
            int f  = n*256 + tid;
            int kl = f >> 5, cf = f & 31;
            int k  = kb + kl;
            const float* src = (cf < 16) ? (We + k*64 + cf*4)
                                         : (Wa + k*64 + (cf-16)*4);
            *(float4*)(sW + kl*192 + cf*4) = *(const float4*)src;
        }
        #pragma unroll
        for (int n = 0; n < 8; ++n) {
            int f  = n*256 + tid;
            int kl = f >> 6, cr = f & 63;
            int k  = kb + kl;
            sW[kl*192 + 128 + cr] = (cr < CC) ? Kmat[cr*64 + k] : 0.f;
        }
    };

    int lane = tid & 63, wvi = tid >> 6;
    int r0 = wvi * 16;

    float accE[16], accA[16], accS[16];
    #pragma unroll
    for (int r = 0; r < 16; ++r) { accE[r] = 0.f; accA[r] = 0.f; accS[r] = 0.f; }

    stageW(0);
    __syncthreads();

    #pragma unroll 2
    for (int k4 = 0; k4 < 8; ++k4) {
        float wE[4], wA4[4], wS[4];
        #pragma unroll
        for (int kk = 0; kk < 4; ++kk) {
            int krow = (k4*4 + kk)*192;
            wE[kk]  = sW[krow + lane];
            wA4[kk] = sW[krow + 64 + lane];
            wS[kk]  = sW[krow + 128 + lane];
        }
        #pragma unroll
        for (int r = 0; r < 16; ++r) {
            float4 xv = *(const float4*)(sX + (r0+r)*64 + k4*4);
            accE[r] = fmaf(xv.x, wE[0], accE[r]);
            accE[r] = fmaf(xv.y, wE[1], accE[r]);
            accE[r] = fmaf(xv.z, wE[2], accE[r]);
            accE[r] = fmaf(xv.w, wE[3], accE[r]);
            accA[r] = fmaf(xv.x, wA4[0], accA[r]);
            accA[r] = fmaf(xv.y, wA4[1], accA[r]);
            accA[r] = fmaf(xv.z, wA4[2], accA[r]);
            accA[r] = fmaf(xv.w, wA4[3], accA[r]);
            accS[r] = fmaf(xv.x, wS[0], accS[r]);
            accS[r] = fmaf(xv.y, wS[1], accS[r]);
            accS[r] = fmaf(xv.z, wS[2], accS[r]);
            accS[r] = fmaf(xv.w, wS[3], accS[r]);
        }
    }
    __syncthreads();            // done reading sW chunk 0

    stageW(32);
    __syncthreads();

    #pragma unroll 2
    for (int k4 = 0; k4 < 8; ++k4) {
        float wE[4], wA4[4], wS[4];
        #pragma unroll
        for (int kk = 0; kk < 4; ++kk) {
            int krow = (k4*4 + kk)*192;
            wE[kk]  = sW[krow + lane];
            wA4[kk] = sW[krow + 64 + lane];
            wS[kk]  = sW[krow + 128 + lane];
        }
        #pragma unroll
        for (int r = 0; r < 16; ++r) {
            float4 xv = *(const float4*)(sX + (r0+r)*64 + 32 + k4*4);
            accE[r] = fmaf(xv.x, wE[0], accE[r]);
            accE[r] = fmaf(xv.y, wE[1], accE[r]);
            accE[r] = fmaf(xv.z, wE[2], accE[r]);
            accE[r] = fmaf(xv.w, wE[3], accE[r]);
            accA[r] = fmaf(xv.x, wA4[0], accA[r]);
            accA[r] = fmaf(xv.y, wA4[1], accA[r]);
            accA[r] = fmaf(xv.z, wA4[2], accA[r]);
            accA[r] = fmaf(xv.w, wA4[3], accA[r]);
            accS[r] = fmaf(xv.x, wS[0], accS[r]);
            accS[r] = fmaf(xv.y, wS[1], accS[r]);
            accS[r] = fmaf(xv.z, wS[2], accS[r]);
            accS[r] = fmaf(xv.w, wS[3], accS[r]);
        }
    }

    // ---- stage 2: per-row nonlinearity + packing, straight from regs ----
    float bev = be[lane], bav = ba[lane];

    #pragma unroll
    for (int r = 0; r < 16; ++r) {
        int rr = r0 + r;
        int grow = base + rr;

        float s = (lane < CC) ? accS[r] : -1e30f;
        float mx = s;
        #pragma unroll
        for (int o = 32; o >= 1; o >>= 1) mx = fmaxf(mx, __shfl_xor(mx, o));
        float p = (lane < CC) ? expf(s - mx) : 0.f;
        float sum = p;
        #pragma unroll
        for (int o = 32; o >= 1; o >>= 1) sum += __shfl_xor(sum, o);
        float wsm = p / sum;

        if (bt == 0) {
            float erv = 1.f / (1.f + expf(-(accE[r] + bev)));
            float adv = tanhf(accA[r] + bav);
            int bs = grow >> 4, il = grow & 15;
            *(float2*)(eaW + (size_t)bs*EA_ST + il*128 + lane*2) =
                make_float2(erv, adv);
            int b = bs / SS, s2 = bs - b*SS;
            if (lane < 52) {
                int omx = lane >> 2, j = lane & 3;
                wrecW[(((size_t)(b*NCH + omx)*SS + s2)*17 + il)*4 + j] =
                    (lane < CC) ? wsm : 0.f;
            }
            if (il == LL-1) le_last[(size_t)bs*DD + lane] = sX[rr*64 + lane];
        } else if (bt == 1) {
            int qrow = grow;
            int b = qrow / SS, s2 = qrow - b*SS;
            if (lane < 52) {
                int omx = lane >> 2, j = lane & 3;
                wrecW[(((size_t)(b*NCH + omx)*SS + s2)*17 + 16)*4 + j] =
                    (lane < CC) ? wsm : 0.f;
            }
            q_e_o[(size_t)qrow*DD + lane] = sX[rr*64 + lane];
        } else {
            float erv = 1.f / (1.f + expf(-(accE[r] + bev)));
            float adv = tanhf(accA[r] + bav);
            int qrow = grow;
            *(float2*)(eaW + (size_t)qrow*EA_ST + 2048 + lane*2) =
                make_float2(erv, adv);
        }
    }
}

// =====================================================================
// Phase A v3: sequential scan with NO VMEM stores in the loop.
// Per-step partial reductions go to LDS (ds_write -> lgkmcnt, so the
// vmcnt chain contains ONLY the ea/w prefetch loads); one bulk coalesced
// float4 copy at kernel end writes per-(om,b) partial buffers. No atomics.
// One 64-thread block (1 wave) per (b, c-chunk); blockIdx = om*32+b keeps
// the 13 blocks of a batch element on one XCD for ea L2 dedup.
// =====================================================================
__global__ __launch_bounds__(64) void phaseA_kernel(
    const float* __restrict__ M0,
    const float* __restrict__ ea, const float* __restrict__ wrec,
    float* __restrict__ PqP, float* __restrict__ PlP)
{
    int om   = blockIdx.x >> 5;     // 0..12
    int b    = blockIdx.x & 31;     // 0..31
    int lane = threadIdx.x;
    int c0   = om * 4;

    __shared__ __align__(16) float wbuf[2][W_ST];
    __shared__ __align__(16) float sPq[SS*DD];   // 12.8 KB
    __shared__ __align__(16) float sPl[SS*DD];   // 12.8 KB

    float M[4];
    #pragma unroll
    for (int i = 0; i < 4; ++i) {
        int c = c0 + i;
        M[i] = (c < CC) ? M0[c*DD + lane] : 0.f;
    }

    const float* eb = ea   + (size_t)b*SS*EA_ST + lane*2;
    const float* wb = wrec + (size_t)(b*NCH + om)*SS*W_ST;

    float2 ea0[17], ea1[17];

    // prologue: load step 0 (ea -> regs, w -> wbuf[0])
    #pragma unroll
    for (int il = 0; il < 17; ++il)
        ea0[il] = *(const float2*)(eb + il*128);
    if (lane < 17)
        *(float4*)&wbuf[0][lane*4] = *(const float4*)(wb + lane*4);

    auto step = [&](int s, float2 (&cur)[17], float2 (&nxt)[17], int wbsel) {
        bool pf = (s < SS-1);
        float4 rw;
        if (pf) {
            const float* eg = eb + (size_t)(s+1)*EA_ST;
            #pragma unroll
            for (int il = 0; il < 17; ++il)
                nxt[il] = *(const float2*)(eg + il*128);
            if (lane < 17)
                rw = *(const float4*)(wb + (size_t)(s+1)*W_ST + lane*4);
        }

        // ---- compute step s ----
        float4 qw = *(const float4*)&wbuf[wbsel][64];   // q-chunk w (slot 16)
        float qr;
        qr = qw.x * M[0];
        qr = fmaf(qw.y, M[1], qr);
        qr = fmaf(qw.z, M[2], qr);
        qr = fmaf(qw.w, M[3], qr);

        float a0 = 0.f, a1 = 0.f, a2 = 0.f, a3 = 0.f;
        #pragma unroll
        for (int il = 0; il < 16; ++il) {
            float4 w = *(const float4*)&wbuf[wbsel][il*4];
            float e = cur[il].x, a = cur[il].y;
            a0 = fmaf(w.x, M[0], a0);
            a1 = fmaf(w.y, M[1], a1);
            a2 = fmaf(w.z, M[2], a2);
            a3 = fmaf(w.w, M[3], a3);
            M[0] = fmaf(w.x, fmaf(-e, M[0], a), M[0]);
            M[1] = fmaf(w.y, fmaf(-e, M[1], a), M[1]);
            M[2] = fmaf(w.z, fmaf(-e, M[2], a), M[2]);
            M[3] = fmaf(w.w, fmaf(-e, M[3], a), M[3]);
        }

        // per-step partials -> LDS (lgkmcnt domain, not vmcnt)
        sPq[s*DD + lane] = qr;
        sPl[s*DD + lane] = (a0 + a1) + (a2 + a3);

        { // final q-write
            float e = cur[16].x, a = cur[16].y;
            M[0] = fmaf(qw.x, fmaf(-e, M[0], a), M[0]);
            M[1] = fmaf(qw.y, fmaf(-e, M[1], a), M[1]);
            M[2] = fmaf(qw.z, fmaf(-e, M[2], a), M[2]);
            M[3] = fmaf(qw.w, fmaf(-e, M[3], a), M[3]);
        }

        // write next w-record late (vmcnt wait lands after compute)
        if (pf && lane < 17)
            *(float4*)&wbuf[wbsel ^ 1][lane*4] = rw;
    };

    for (int s = 0; s < SS; s += 2) {
        step(s,     ea0, ea1, 0);
        step(s + 1, ea1, ea0, 1);
    }

    // ---- epilogue: bulk coalesced copy LDS partials -> global ----
    // (single wave: LDS ops are in-order within the wave, no barrier)
    float* pqo = PqP + (size_t)(om*BB + b)*SS*DD;
    float* plo = PlP + (size_t)(om*BB + b)*SS*DD;
    for (int f = lane; f < SS*DD/4; f += 64) {
        *(float4*)(pqo + f*4) = *(const float4*)(sPq + f*4);
        *(float4*)(plo + f*4) = *(const float4*)(sPl + f*4);
    }
}

// =====================================================================
// Phase B v3.2: mastery (13-way partial sum) -> LN -> MLP -> out.
// GEMMs unchanged from round 8 (register-streamed, full-K).
// =====================================================================
__global__ __launch_bounds__(256) void phaseB_kernel(
    const float* __restrict__ PqP, const float* __restrict__ PlP,
    const float* __restrict__ q_e_i, const float* __restrict__ le_last,
    const float* __restrict__ ln_g, const float* __restrict__ ln_b,
    const float* __restrict__ W0, const float* __restrict__ b0,
    const float* __restrict__ W1, const float* __restrict__ b1,
    const float* __restrict__ Wout, const float* __restrict__ bout,
    float* __restrict__ out)
{
    __shared__ float m[8][H4];          // 8 KB
    __shared__ float h[8][H4];          // 8 KB
    __shared__ float red[8][4];

    int j = threadIdx.x;                // owns output column j
    int g0 = blockIdx.x * 8;
    int lane = j & 63, wv = j >> 6;

    // ---- build mastery = [q_read | q_e | l_read | le_last] ----
    int seg = j >> 6, dd = j & 63;
    #pragma unroll
    for (int r = 0; r < 8; ++r) {
        int g = g0 + r;
        float v;
        if (seg == 0) {
            v = 0.f;
            #pragma unroll
            for (int om = 0; om < NCH; ++om)
                v += PqP[((size_t)om*BB*SS + g)*DD + dd];
        } else if (seg == 1) {
            v = q_e_i[(size_t)g*DD + dd];
        } else if (seg == 2) {
            v = 0.f;
            #pragma unroll
            for (int om = 0; om < NCH; ++om)
                v += PlP[((size_t)om*BB*SS + g)*DD + dd];
        } else {
            v = le_last[(size_t)g*DD + dd];
        }
        m[r][j] = v;
    }
    __syncthreads();

    // ---- LayerNorm: wave wv normalizes rows wv and wv+4 ----
    #pragma unroll
    for (int rr = 0; rr < 2; ++rr) {
        int r = wv + rr*4;
        float4 v4 = *(((const float4*)&m[r][0]) + lane);
        float s1 = v4.x + v4.y + v4.z + v4.w;
        float s2 = v4.x*v4.x + v4.y*v4.y + v4.z*v4.z + v4.w*v4.w;
        #pragma unroll
        for (int o = 32; o >= 1; o >>= 1) {
            s1 += __shfl_xor(s1, o);
            s2 += __shfl_xor(s2, o);
        }
        float mu  = s1 * (1.f/256.f);
        float var = s2 * (1.f/256.f) - mu*mu;
        float is  = rsqrtf(var + 1e-5f);
        float4 g4 = *(((const float4*)ln_g) + lane);
        float4 b4 = *(((const float4*)ln_b) + lane);
        float4 o4;
        o4.x = (v4.x - mu)*is*g4.x + b4.x;
        o4.y = (v4.y - mu)*is*g4.y + b4.y;
        o4.z = (v4.z - mu)*is*g4.z + b4.z;
        o4.w = (v4.w - mu)*is*g4.w + b4.w;
        *(((float4*)&m[r][0]) + lane) = o4;
    }
    __syncthreads();

    // ---- GEMM1: acc = m @ W0 + b0 (NBAT=16 batches of KBAT=16 k) ----
    const float* Wp = W0 + j;
    float acc[8];
    {
        float bj = b0[j];
        #pragma unroll
        for (int r = 0; r < 8; ++r) acc[r] = bj;
    }
    {
        float wA[KBAT], wB[KBAT];
        #pragma unroll
        for (int t = 0; t < KBAT; ++t) wA[t] = Wp[(size_t)t*H4];
        #pragma unroll 1
        for (int kb = 0; kb < NBAT; kb += 2) {
            #pragma unroll
            for (int t = 0; t < KBAT; ++t)
                wB[t] = Wp[(size_t)((kb+1)*KBAT + t)*H4];
            #pragma unroll
            for (int t4 = 0; t4 < KBAT/4; ++t4) {
                #pragma unroll
                for (int r = 0; r < 8; ++r) {
                    float4 mv = *(const float4*)&m[r][kb*KBAT + t4*4];
                    acc[r] = fmaf(mv.x, wA[t4*4+0], acc[r]);
                    acc[r] = fmaf(mv.y, wA[t4*4+1], acc[r]);
                    acc[r] = fmaf(mv.z, wA[t4*4+2], acc[r]);
                    acc[r] = fmaf(mv.w, wA[t4*4+3], acc[r]);
                }
            }
            if (kb + 2 < NBAT) {
                #pragma unroll
                for (int t = 0; t < KBAT; ++t)
                    wA[t] = Wp[(size_t)((kb+2)*KBAT + t)*H4];
            }
            #pragma unroll
            for (int t4 = 0; t4 < KBAT/4; ++t4) {
                #pragma unroll
                for (int r = 0; r < 8; ++r) {
                    float4 mv = *(const float4*)&m[r][(kb+1)*KBAT + t4*4];
                    acc[r] = fmaf(mv.x, wB[t4*4+0], acc[r]);
                    acc[r] = fmaf(mv.y, wB[t4*4+1], acc[r]);
                    acc[r] = fmaf(mv.z, wB[t4*4+2], acc[r]);
                    acc[r] = fmaf(mv.w, wB[t4*4+3], acc[r]);
                }
            }
        }
    }
    #pragma unroll
    for (int r = 0; r < 8; ++r) h[r][j] = fmaxf(acc[r], 0.f);
    __syncthreads();

    // ---- GEMM2: a2 = h @ W1 + b1 (same schedule) ----
    const float* Wp1 = W1 + j;
    float a2[8];
    {
        float bj = b1[j];
        #pragma unroll
        for (int r = 0; r < 8; ++r) a2[r] = bj;
    }
    {
        float wA[KBAT], wB[KBAT];
        #pragma unroll
        for (int t = 0; t < KBAT; ++t) wA[t] = Wp1[(size_t)t*H4];
        #pragma unroll 1
        for (int kb = 0; kb < NBAT; kb += 2) {
            #pragma unroll
            for (int t = 0; t < KBAT; ++t)
                wB[t] = Wp1[(size_t)((kb+1)*KBAT + t)*H4];
            #pragma unroll
            for (int t4 = 0; t4 < KBAT/4; ++t4) {
                #pragma unroll
                for (int r = 0; r < 8; ++r) {
                    float4 hv = *(const float4*)&h[r][kb*KBAT + t4*4];
                    a2[r] = fmaf(hv.x, wA[t4*4+0], a2[r]);
                    a2[r] = fmaf(hv.y, wA[t4*4+1], a2[r]);
                    a2[r] = fmaf(hv.z, wA[t4*4+2], a2[r]);
                    a2[r] = fmaf(hv.w, wA[t4*4+3], a2[r]);
                }
            }
            if (kb + 2 < NBAT) {
                #pragma unroll
                for (int t = 0; t < KBAT; ++t)
                    wA[t] = Wp1[(size_t)((kb+2)*KBAT + t)*H4];
            }
            #pragma unroll
            for (int t4 = 0; t4 < KBAT/4; ++t4) {
                #pragma unroll
                for (int r = 0; r < 8; ++r) {
                    float4 hv = *(const float4*)&h[r][(kb+1)*KBAT + t4*4];
                    a2[r] = fmaf(hv.x, wB[t4*4+0], a2[r]);
                    a2[r] = fmaf(hv.y, wB[t4*4+1], a2[r]);
                    a2[r] = fmaf(hv.z, wB[t4*4+2], a2[r]);
                    a2[r] = fmaf(hv.w, wB[t4*4+3], a2[r]);
                }
            }
        }
    }

    // ---- pred = sigmoid(h1 . Wout + bout) ----
    float wo = Wout[j];
    #pragma unroll
    for (int r = 0; r < 8; ++r) {
        float v = a2[r] * wo;
        #pragma unroll
        for (int o = 32; o >= 1; o >>= 1) v += __shfl_xor(v, o);
        if (lane == 0) red[r][wv] = v;
    }
    __syncthreads();
    if (j < 8) {
        float t = red[j][0] + red[j][1] + red[j][2] + red[j][3] + bout[0];
        out[g0 + j] = 1.f / (1.f + expf(-t));
    }
}

// =====================================================================
extern "C" void kernel_launch(void* const* d_in, const int* in_sizes, int n_in,
                              void* d_out, int out_size, void* d_ws, size_t ws_size,
                              hipStream_t stream)
{
    const int*   q_data  = (const int*)  d_in[0];
    const int*   qa_data = (const int*)  d_in[1];
    const int*   l_data  = (const int*)  d_in[2];
    // d_in[3] users: unused by reference forward
    const float* Kmat    = (const float*)d_in[4];
    const float* q_embed = (const float*)d_in[5];
    const float* qa_embed= (const float*)d_in[6];
    // d_in[7] u_embed: unused by reference forward
    const float* M0      = (const float*)d_in[8];
    const float* W_e     = (const float*)d_in[9];
    const float* b_e     = (const float*)d_in[10];
    const float* W_a     = (const float*)d_in[11];
    const float* b_a     = (const float*)d_in[12];
    const float* ln_g    = (const float*)d_in[13];
    const float* ln_b    = (const float*)d_in[14];
    const float* W0      = (const float*)d_in[15];
    const float* b0      = (const float*)d_in[16];
    const float* W1      = (const float*)d_in[17];
    const float* b1      = (const float*)d_in[18];
    const float* W_out   = (const float*)d_in[19];
    const float* b_out   = (const float*)d_in[20];

    float* ws = (float*)d_ws;
    float* eaW     = ws + OFF_EA;
    float* wrecW   = ws + OFF_W;
    float* PqP     = ws + OFF_PQP;
    float* PlP     = ws + OFF_PLP;
    float* q_e     = ws + OFF_QE;
    float* le_last = ws + OFF_LELAST;

    float* out = (float*)d_out;

    k0_kernel<<<NGB, 256, 0, stream>>>(q_data, qa_data, l_data,
                                       Kmat, q_embed, qa_embed,
                                       W_e, W_a, b_e, b_a,
                                       eaW, wrecW,
                                       q_e, le_last);
    phaseA_kernel<<<BB*NCH, 64, 0, stream>>>(M0, eaW, wrecW, PqP, PlP);
    phaseB_kernel<<<NROWS_Q/8, 256, 0, stream>>>(PqP, PlP, q_e, le_last,
                                                 ln_g, ln_b, W0, b0, W1, b1,
                                                 W_out, b_out, out);
}

// Round 11
// 195.555 us; speedup vs baseline: 1.3382x; 1.0198x over previous
//
#include <hip/hip_runtime.h>
#include <math.h>

// Problem constants
#define BB 32
#define SS 50
#define LL 16
#define CC 50
#define DD 64
#define NCH 13           // c-chunks of 4 rows (C=50 padded to 52)
#define H4 256
#define NROWS_Q (BB*SS)            // 1600
#define NROWS_L (BB*SS*LL)         // 25600

#define EA_ST 2176       // floats per (b,s) ea record: 17 slots * 128
#define W_ST  68         // floats per (b,om,s) w record: 17 * 4

// GEMM geometry for k0
#define RB 32                       // rows per block (32 -> 900 blocks, 3.5/CU)
#define NBLK_L (NROWS_L/RB)         // 800
#define NBLK_Q (NROWS_Q/RB)         // 50
#define NGB (NBLK_L + 2*NBLK_Q)     // 900

// phaseB k-batching: 16 k-rows per register batch
#define KBAT 16
#define NBAT (H4/KBAT)              // 16 batches — MUST cover all of H4

// Layout invariants shared by k0 (producer) and phaseA (consumer)
static_assert(EA_ST == 17*128, "ea record: 17 slots x 64 lanes x float2");
static_assert(W_ST == 17*4, "w record: 17 slots x 4 chunk-cols");
static_assert(SS == 50, "phaseA pipeline is hand-unrolled for SS=50 (48+2)");
static_assert(NROWS_L % RB == 0 && NROWS_Q % RB == 0, "GEMM row blocking");
static_assert(RB % 16 == 0, "l-row il-groups must not straddle blocks");
static_assert(NBAT*KBAT == H4 && NBAT % 2 == 0,
              "phaseB k-loop must cover ALL of H4 in pairs of batches");
static_assert(SS*DD % 4 == 0, "phaseA partial copy uses float4");

// ---------------- workspace layout (floats) ----------------
#define OFF_EA     ((size_t)0)
#define OFF_W      (OFF_EA + (size_t)NROWS_Q*EA_ST)            // +3,481,600
#define OFF_PQP    (OFF_W  + (size_t)BB*NCH*SS*W_ST)           // +1,414,400
#define OFF_PLP    (OFF_PQP + (size_t)NCH*BB*SS*DD)            // +1,331,200
#define OFF_QE     (OFF_PLP + (size_t)NCH*BB*SS*DD)            // +1,331,200
#define OFF_LELAST (OFF_QE + (size_t)NROWS_Q*DD)               // +102,400
// total = 7,763,200 floats = 29.6 MB

// =====================================================================
// K0 v3: register-output precompute GEMM, RB=32 rows/block, 900 blocks
// (~3.5 blocks/CU — doubles in-flight embedding gathers vs RB=64).
// Wave owns 8 rows; lane owns output cols {lane,64+lane,128+lane}.
// sW staged k-major [32][192] in two k-chunks (24 KB); conflict-free
// b32 reads; sX reads wave-uniform b128. LDS 32 KB.
// =====================================================================
__global__ __launch_bounds__(256, 4) void k0_kernel(
    const int* __restrict__ qd, const int* __restrict__ qadx,
    const int* __restrict__ ld,
    const float* __restrict__ Kmat, const float* __restrict__ qemb,
    const float* __restrict__ qaemb,
    const float* __restrict__ We, const float* __restrict__ Wa,
    const float* __restrict__ be, const float* __restrict__ ba,
    float* __restrict__ eaW, float* __restrict__ wrecW,
    float* __restrict__ q_e_o, float* __restrict__ le_last)
{
    __shared__ float sX[RB*DD];         // 8 KB   [32 rows][64 k]
    __shared__ float sW[32*192];        // 24 KB  [32 k][192 cols], 2 chunks

    int tid = threadIdx.x;
    int bid = blockIdx.x;

    int bt, base;
    if (bid < NBLK_L)              { bt = 0; base = bid*RB; }
    else if (bid < NBLK_L+NBLK_Q)  { bt = 1; base = (bid-NBLK_L)*RB; }
    else                           { bt = 2; base = (bid-NBLK_L-NBLK_Q)*RB; }

    // ---- stage X tile (embedding gather, coalesced float4) ----
    {
        const int*   idsrc = (bt==0) ? ld : (bt==1) ? qd : qadx;
        const float* tab   = (bt==2) ? qaemb : qemb;
        for (int idx = tid; idx < RB*16; idx += 256) {
            int r = idx >> 4, q = idx & 15;
            int id = idsrc[base + r];
            *(float4*)(sX + r*64 + q*4) =
                *(const float4*)(tab + (size_t)id*DD + q*4);
        }
    }

    // W chunk staging: k-rows [kb, kb+32) of Wcat[64][192] = [W_e|W_a|K^T]
    auto stageW = [&](int kb) {
        #pragma unroll
        for (int n = 0; n < 4; ++n) {
            int f  = n*256 + tid;
            int kl = f >> 5, cf = f & 31;
            int k  = kb + kl;
            const float* src = (cf < 16) ? (We + k*64 + cf*4)
                                         : (Wa + k*64 + (cf-16)*4);
            *(float4*)(sW + kl*192 + cf*4) = *(const float4*)src;
        }
        #pragma unroll
        for (int n = 0; n < 8; ++n) {
            int f  = n*256 + tid;
            int kl = f >> 6, cr = f & 63;
            int k  = kb + kl;
            sW[kl*192 + 128 + cr] = (cr < CC) ? Kmat[cr*64 + k] : 0.f;
        }
    };

    int lane = tid & 63, wvi = tid >> 6;
    int r0 = wvi * 8;

    float accE[8], accA[8], accS[8];
    #pragma unroll
    for (int r = 0; r < 8; ++r) { accE[r] = 0.f; accA[r] = 0.f; accS[r] = 0.f; }

    stageW(0);
    __syncthreads();

    #pragma unroll 2
    for (int k4 = 0; k4 < 8; ++k4) {
        float wE[4], wA4[4], wS[4];
        #pragma unroll
        for (int kk = 0; kk < 4; ++kk) {
            int krow = (k4*4 + kk)*192;
            wE[kk]  = sW[krow + lane];
            wA4[kk] = sW[krow + 64 + lane];
            wS[kk]  = sW[krow + 128 + lane];
        }
        #pragma unroll
        for (int r = 0; r < 8; ++r) {
            float4 xv = *(const float4*)(sX + (r0+r)*64 + k4*4);
            accE[r] = fmaf(xv.x, wE[0], accE[r]);
            accE[r] = fmaf(xv.y, wE[1], accE[r]);
            accE[r] = fmaf(xv.z, wE[2], accE[r]);
            accE[r] = fmaf(xv.w, wE[3], accE[r]);
            accA[r] = fmaf(xv.x, wA4[0], accA[r]);
            accA[r] = fmaf(xv.y, wA4[1], accA[r]);
            accA[r] = fmaf(xv.z, wA4[2], accA[r]);
            accA[r] = fmaf(xv.w, wA4[3], accA[r]);
            accS[r] = fmaf(xv.x, wS[0], accS[r]);
            accS[r] = fmaf(xv.y, wS[1], accS[r]);
            accS[r] = fmaf(xv.z, wS[2], accS[r]);
            accS[r] = fmaf(xv.w, wS[3], accS[r]);
        }
    }
    __syncthreads();            // done reading sW chunk 0

    stageW(32);
    __syncthreads();

    #pragma unroll 2
    for (int k4 = 0; k4 < 8; ++k4) {
        float wE[4], wA4[4], wS[4];
        #pragma unroll
        for (int kk = 0; kk < 4; ++kk) {
            int krow = (k4*4 + kk)*192;
            wE[kk]  = sW[krow + lane];
            wA4[kk] = sW[krow + 64 + lane];
            wS[kk]  = sW[krow + 128 + lane];
        }
        #pragma unroll
        for (int r = 0; r < 8; ++r) {
            float4 xv = *(const float4*)(sX + (r0+r)*64 + 32 + k4*4);
            accE[r] = fmaf(xv.x, wE[0], accE[r]);
            accE[r] = fmaf(xv.y, wE[1], accE[r]);
            accE[r] = fmaf(xv.z, wE[2], accE[r]);
            accE[r] = fmaf(xv.w, wE[3], accE[r]);
            accA[r] = fmaf(xv.x, wA4[0], accA[r]);
            accA[r] = fmaf(xv.y, wA4[1], accA[r]);
            accA[r] = fmaf(xv.z, wA4[2], accA[r]);
            accA[r] = fmaf(xv.w, wA4[3], accA[r]);
            accS[r] = fmaf(xv.x, wS[0], accS[r]);
            accS[r] = fmaf(xv.y, wS[1], accS[r]);
            accS[r] = fmaf(xv.z, wS[2], accS[r]);
            accS[r] = fmaf(xv.w, wS[3], accS[r]);
        }
    }

    // ---- stage 2: per-row nonlinearity + packing, straight from regs ----
    float bev = be[lane], bav = ba[lane];

    #pragma unroll
    for (int r = 0; r < 8; ++r) {
        int rr = r0 + r;
        int grow = base + rr;

        float s = (lane < CC) ? accS[r] : -1e30f;
        float mx = s;
        #pragma unroll
        for (int o = 32; o >= 1; o >>= 1) mx = fmaxf(mx, __shfl_xor(mx, o));
        float p = (lane < CC) ? expf(s - mx) : 0.f;
        float sum = p;
        #pragma unroll
        for (int o = 32; o >= 1; o >>= 1) sum += __shfl_xor(sum, o);
        float wsm = p / sum;

        if (bt == 0) {
            float erv = 1.f / (1.f + expf(-(accE[r] + bev)));
            float adv = tanhf(accA[r] + bav);
            int bs = grow >> 4, il = grow & 15;
            *(float2*)(eaW + (size_t)bs*EA_ST + il*128 + lane*2) =
                make_float2(erv, adv);
            int b = bs / SS, s2 = bs - b*SS;
            if (lane < 52) {
                int omx = lane >> 2, j = lane & 3;
                wrecW[(((size_t)(b*NCH + omx)*SS + s2)*17 + il)*4 + j] =
                    (lane < CC) ? wsm : 0.f;
            }
            if (il == LL-1) le_last[(size_t)bs*DD + lane] = sX[rr*64 + lane];
        } else if (bt == 1) {
            int qrow = grow;
            int b = qrow / SS, s2 = qrow - b*SS;
            if (lane < 52) {
                int omx = lane >> 2, j = lane & 3;
                wrecW[(((size_t)(b*NCH + omx)*SS + s2)*17 + 16)*4 + j] =
                    (lane < CC) ? wsm : 0.f;
            }
            q_e_o[(size_t)qrow*DD + lane] = sX[rr*64 + lane];
        } else {
            float erv = 1.f / (1.f + expf(-(accE[r] + bev)));
            float adv = tanhf(accA[r] + bav);
            int qrow = grow;
            *(float2*)(eaW + (size_t)qrow*EA_ST + 2048 + lane*2) =
                make_float2(erv, adv);
        }
    }
}

// =====================================================================
// Phase A v4: sequential scan, 2-step-deep ea register pipeline
// (3 named buffers, unroll-by-3: 48 steps + 2-step epilogue).
// w-record: load issued FIRST in each step (w(s+2) -> rw reg), LDS write
// delayed one full step (w(s+1), loaded last step, written before this
// step's compute) -> its vmcnt wait lands ~1 step (~350cy) after issue.
// Per-step partials go to LDS; one bulk float4 copy at the end. No
// atomics, no VMEM stores in the loop.
// =====================================================================
__global__ __launch_bounds__(64) void phaseA_kernel(
    const float* __restrict__ M0,
    const float* __restrict__ ea, const float* __restrict__ wrec,
    float* __restrict__ PqP, float* __restrict__ PlP)
{
    int om   = blockIdx.x >> 5;     // 0..12
    int b    = blockIdx.x & 31;     // 0..31
    int lane = threadIdx.x;
    int c0   = om * 4;

    __shared__ __align__(16) float wbuf[2][W_ST];
    __shared__ __align__(16) float sPq[SS*DD];   // 12.8 KB
    __shared__ __align__(16) float sPl[SS*DD];   // 12.8 KB

    float M[4];
    #pragma unroll
    for (int i = 0; i < 4; ++i) {
        int c = c0 + i;
        M[i] = (c < CC) ? M0[c*DD + lane] : 0.f;
    }

    const float* eb = ea   + (size_t)b*SS*EA_ST + lane*2;
    const float* wb = wrec + (size_t)(b*NCH + om)*SS*W_ST;

    float2 eaA[17], eaB[17], eaC[17];
    float4 rw0, rw1, rw2;

    // ---- prologue ----
    // eaA = ea(0), eaB = ea(1); wbuf[0] = w(0) (direct); rw0 = w(1)
    #pragma unroll
    for (int il = 0; il < 17; ++il) eaA[il] = *(const float2*)(eb + il*128);
    #pragma unroll
    for (int il = 0; il < 17; ++il) eaB[il] = *(const float2*)(eb + EA_ST + il*128);
    if (lane < 17) {
        float4 w0 = *(const float4*)(wb + lane*4);
        *(float4*)&wbuf[0][lane*4] = w0;
        rw0 = *(const float4*)(wb + (size_t)W_ST + lane*4);
    }

    // step: compute step s from cur + wbuf[s&1].
    //  - issue w(s+2) -> rwL   (first, so its wait is cheap next step)
    //  - issue ea(s+2) -> nxt
    //  - write rwW (=w(s+1), loaded LAST step) -> wbuf[(s+1)&1]
    //  - compute; partials -> LDS
    auto step = [&](int s, float2 (&cur)[17], float2 (&nxt)[17],
                    float4& rwW, float4& rwL, bool doLoad, bool doWrite) {
        if (doLoad && lane < 17)
            rwL = *(const float4*)(wb + (size_t)(s+2)*W_ST + lane*4);
        if (doLoad) {
            const float* eg = eb + (size_t)(s+2)*EA_ST;
            #pragma unroll
            for (int il = 0; il < 17; ++il)
                nxt[il] = *(const float2*)(eg + il*128);
        }
        if (doWrite && lane < 17)
            *(float4*)&wbuf[(s+1)&1][lane*4] = rwW;

        // ---- compute step s from wbuf[s&1] ----
        const float* wbp = &wbuf[s&1][0];
        float4 qw = *(const float4*)(wbp + 64);      // q-chunk w (slot 16)
        float qr;
        qr = qw.x * M[0];
        qr = fmaf(qw.y, M[1], qr);
        qr = fmaf(qw.z, M[2], qr);
        qr = fmaf(qw.w, M[3], qr);

        float a0 = 0.f, a1 = 0.f, a2 = 0.f, a3 = 0.f;
        #pragma unroll
        for (int il = 0; il < 16; ++il) {
            float4 w = *(const float4*)(wbp + il*4);
            float e = cur[il].x, a = cur[il].y;
            a0 = fmaf(w.x, M[0], a0);
            a1 = fmaf(w.y, M[1], a1);
            a2 = fmaf(w.z, M[2], a2);
            a3 = fmaf(w.w, M[3], a3);
            M[0] = fmaf(w.x, fmaf(-e, M[0], a), M[0]);
            M[1] = fmaf(w.y, fmaf(-e, M[1], a), M[1]);
            M[2] = fmaf(w.z, fmaf(-e, M[2], a), M[2]);
            M[3] = fmaf(w.w, fmaf(-e, M[3], a), M[3]);
        }

        sPq[s*DD + lane] = qr;
        sPl[s*DD + lane] = (a0 + a1) + (a2 + a3);

        { // final q-write
            float e = cur[16].x, a = cur[16].y;
            M[0] = fmaf(qw.x, fmaf(-e, M[0], a), M[0]);
            M[1] = fmaf(qw.y, fmaf(-e, M[1], a), M[1]);
            M[2] = fmaf(qw.z, fmaf(-e, M[2], a), M[2]);
            M[3] = fmaf(qw.w, fmaf(-e, M[3], a), M[3]);
        }
    };

    // main loop: steps 0..47 (16 iterations x 3 steps)
    for (int s = 0; s < 48; s += 3) {
        step(s,     eaA, eaC, rw0, rw1, true, true);
        step(s + 1, eaB, eaA, rw1, rw2, true, true);
        step(s + 2, eaC, eaB, rw2, rw0, true, true);
    }
    // epilogue: steps 48, 49 (no loads; 49 has no w-write)
    step(48, eaA, eaC, rw0, rw1, false, true);
    step(49, eaB, eaA, rw1, rw2, false, false);

    // ---- epilogue: bulk coalesced copy LDS partials -> global ----
    float* pqo = PqP + (size_t)(om*BB + b)*SS*DD;
    float* plo = PlP + (size_t)(om*BB + b)*SS*DD;
    for (int f = lane; f < SS*DD/4; f += 64) {
        *(float4*)(pqo + f*4) = *(const float4*)(sPq + f*4);
        *(float4*)(plo + f*4) = *(const float4*)(sPl + f*4);
    }
}

// =====================================================================
// Phase B v3.2: mastery (13-way partial sum) -> LN -> MLP -> out.
// (unchanged from round 9)
// =====================================================================
__global__ __launch_bounds__(256) void phaseB_kernel(
    const float* __restrict__ PqP, const float* __restrict__ PlP,
    const float* __restrict__ q_e_i, const float* __restrict__ le_last,
    const float* __restrict__ ln_g, const float* __restrict__ ln_b,
    const float* __restrict__ W0, const float* __restrict__ b0,
    const float* __restrict__ W1, const float* __restrict__ b1,
    const float* __restrict__ Wout, const float* __restrict__ bout,
    float* __restrict__ out)
{
    __shared__ float m[8][H4];          // 8 KB
    __shared__ float h[8][H4];          // 8 KB
    __shared__ float red[8][4];

    int j = threadIdx.x;                // owns output column j
    int g0 = blockIdx.x * 8;
    int lane = j & 63, wv = j >> 6;

    // ---- build mastery = [q_read | q_e | l_read | le_last] ----
    int seg = j >> 6, dd = j & 63;
    #pragma unroll
    for (int r = 0; r < 8; ++r) {
        int g = g0 + r;
        float v;
        if (seg == 0) {
            v = 0.f;
            #pragma unroll
            for (int om = 0; om < NCH; ++om)
                v += PqP[((size_t)om*BB*SS + g)*DD + dd];
        } else if (seg == 1) {
            v = q_e_i[(size_t)g*DD + dd];
        } else if (seg == 2) {
            v = 0.f;
            #pragma unroll
            for (int om = 0; om < NCH; ++om)
                v += PlP[((size_t)om*BB*SS + g)*DD + dd];
        } else {
            v = le_last[(size_t)g*DD + dd];
        }
        m[r][j] = v;
    }
    __syncthreads();

    // ---- LayerNorm: wave wv normalizes rows wv and wv+4 ----
    #pragma unroll
    for (int rr = 0; rr < 2; ++rr) {
        int r = wv + rr*4;
        float4 v4 = *(((const float4*)&m[r][0]) + lane);
        float s1 = v4.x + v4.y + v4.z + v4.w;
        float s2 = v4.x*v4.x + v4.y*v4.y + v4.z*v4.z + v4.w*v4.w;
        #pragma unroll
        for (int o = 32; o >= 1; o >>= 1) {
            s1 += __shfl_xor(s1, o);
            s2 += __shfl_xor(s2, o);
        }
        float mu  = s1 * (1.f/256.f);
        float var = s2 * (1.f/256.f) - mu*mu;
        float is  = rsqrtf(var + 1e-5f);
        float4 g4 = *(((const float4*)ln_g) + lane);
        float4 b4 = *(((const float4*)ln_b) + lane);
        float4 o4;
        o4.x = (v4.x - mu)*is*g4.x + b4.x;
        o4.y = (v4.y - mu)*is*g4.y + b4.y;
        o4.z = (v4.z - mu)*is*g4.z + b4.z;
        o4.w = (v4.w - mu)*is*g4.w + b4.w;
        *(((float4*)&m[r][0]) + lane) = o4;
    }
    __syncthreads();

    // ---- GEMM1: acc = m @ W0 + b0 (NBAT=16 batches of KBAT=16 k) ----
    const float* Wp = W0 + j;
    float acc[8];
    {
        float bj = b0[j];
        #pragma unroll
        for (int r = 0; r < 8; ++r) acc[r] = bj;
    }
    {
        float wA[KBAT], wB[KBAT];
        #pragma unroll
        for (int t = 0; t < KBAT; ++t) wA[t] = Wp[(size_t)t*H4];
        #pragma unroll 1
        for (int kb = 0; kb < NBAT; kb += 2) {
            #pragma unroll
            for (int t = 0; t < KBAT; ++t)
                wB[t] = Wp[(size_t)((kb+1)*KBAT + t)*H4];
            #pragma unroll
            for (int t4 = 0; t4 < KBAT/4; ++t4) {
                #pragma unroll
                for (int r = 0; r < 8; ++r) {
                    float4 mv = *(const float4*)&m[r][kb*KBAT + t4*4];
                    acc[r] = fmaf(mv.x, wA[t4*4+0], acc[r]);
                    acc[r] = fmaf(mv.y, wA[t4*4+1], acc[r]);
                    acc[r] = fmaf(mv.z, wA[t4*4+2], acc[r]);
                    acc[r] = fmaf(mv.w, wA[t4*4+3], acc[r]);
                }
            }
            if (kb + 2 < NBAT) {
                #pragma unroll
                for (int t = 0; t < KBAT; ++t)
                    wA[t] = Wp[(size_t)((kb+2)*KBAT + t)*H4];
            }
            #pragma unroll
            for (int t4 = 0; t4 < KBAT/4; ++t4) {
                #pragma unroll
                for (int r = 0; r < 8; ++r) {
                    float4 mv = *(const float4*)&m[r][(kb+1)*KBAT + t4*4];
                    acc[r] = fmaf(mv.x, wB[t4*4+0], acc[r]);
                    acc[r] = fmaf(mv.y, wB[t4*4+1], acc[r]);
                    acc[r] = fmaf(mv.z, wB[t4*4+2], acc[r]);
                    acc[r] = fmaf(mv.w, wB[t4*4+3], acc[r]);
                }
            }
        }
    }
    #pragma unroll
    for (int r = 0; r < 8; ++r) h[r][j] = fmaxf(acc[r], 0.f);
    __syncthreads();

    // ---- GEMM2: a2 = h @ W1 + b1 (same schedule) ----
    const float* Wp1 = W1 + j;
    float a2[8];
    {
        float bj = b1[j];
        #pragma unroll
        for (int r = 0; r < 8; ++r) a2[r] = bj;
    }
    {
        float wA[KBAT], wB[KBAT];
        #pragma unroll
        for (int t = 0; t < KBAT; ++t) wA[t] = Wp1[(size_t)t*H4];
        #pragma unroll 1
        for (int kb = 0; kb < NBAT; kb += 2) {
            #pragma unroll
            for (int t = 0; t < KBAT; ++t)
                wB[t] = Wp1[(size_t)((kb+1)*KBAT + t)*H4];
            #pragma unroll
            for (int t4 = 0; t4 < KBAT/4; ++t4) {
                #pragma unroll
                for (int r = 0; r < 8; ++r) {
                    float4 hv = *(const float4*)&h[r][kb*KBAT + t4*4];
                    a2[r] = fmaf(hv.x, wA[t4*4+0], a2[r]);
                    a2[r] = fmaf(hv.y, wA[t4*4+1], a2[r]);
                    a2[r] = fmaf(hv.z, wA[t4*4+2], a2[r]);
                    a2[r] = fmaf(hv.w, wA[t4*4+3], a2[r]);
                }
            }
            if (kb + 2 < NBAT) {
                #pragma unroll
                for (int t = 0; t < KBAT; ++t)
                    wA[t] = Wp1[(size_t)((kb+2)*KBAT + t)*H4];
            }
            #pragma unroll
            for (int t4 = 0; t4 < KBAT/4; ++t4) {
                #pragma unroll
                for (int r = 0; r < 8; ++r) {
                    float4 hv = *(const float4*)&h[r][(kb+1)*KBAT + t4*4];
                    a2[r] = fmaf(hv.x, wB[t4*4+0], a2[r]);
                    a2[r] = fmaf(hv.y, wB[t4*4+1], a2[r]);
                    a2[r] = fmaf(hv.z, wB[t4*4+2], a2[r]);
                    a2[r] = fmaf(hv.w, wB[t4*4+3], a2[r]);
                }
            }
        }
    }

    // ---- pred = sigmoid(h1 . Wout + bout) ----
    float wo = Wout[j];
    #pragma unroll
    for (int r = 0; r < 8; ++r) {
        float v = a2[r] * wo;
        #pragma unroll
        for (int o = 32; o >= 1; o >>= 1) v += __shfl_xor(v, o);
        if (lane == 0) red[r][wv] = v;
    }
    __syncthreads();
    if (j < 8) {
        float t = red[j][0] + red[j][1] + red[j][2] + red[j][3] + bout[0];
        out[g0 + j] = 1.f / (1.f + expf(-t));
    }
}

// =====================================================================
extern "C" void kernel_launch(void* const* d_in, const int* in_sizes, int n_in,
                              void* d_out, int out_size, void* d_ws, size_t ws_size,
                              hipStream_t stream)
{
    const int*   q_data  = (const int*)  d_in[0];
    const int*   qa_data = (const int*)  d_in[1];
    const int*   l_data  = (const int*)  d_in[2];
    // d_in[3] users: unused by reference forward
    const float* Kmat    = (const float*)d_in[4];
    const float* q_embed = (const float*)d_in[5];
    const float* qa_embed= (const float*)d_in[6];
    // d_in[7] u_embed: unused by reference forward
    const float* M0      = (const float*)d_in[8];
    const float* W_e     = (const float*)d_in[9];
    const float* b_e     = (const float*)d_in[10];
    const float* W_a     = (const float*)d_in[11];
    const float* b_a     = (const float*)d_in[12];
    const float* ln_g    = (const float*)d_in[13];
    const float* ln_b    = (const float*)d_in[14];
    const float* W0      = (const float*)d_in[15];
    const float* b0      = (const float*)d_in[16];
    const float* W1      = (const float*)d_in[17];
    const float* b1      = (const float*)d_in[18];
    const float* W_out   = (const float*)d_in[19];
    const float* b_out   = (const float*)d_in[20];

    float* ws = (float*)d_ws;
    float* eaW     = ws + OFF_EA;
    float* wrecW   = ws + OFF_W;
    float* PqP     = ws + OFF_PQP;
    float* PlP     = ws + OFF_PLP;
    float* q_e     = ws + OFF_QE;
    float* le_last = ws + OFF_LELAST;

    float* out = (float*)d_out;

    k0_kernel<<<NGB, 256, 0, stream>>>(q_data, qa_data, l_data,
                                       Kmat, q_embed, qa_embed,
                                       W_e, W_a, b_e, b_a,
                                       eaW, wrecW,
                                       q_e, le_last);
    phaseA_kernel<<<BB*NCH, 64, 0, stream>>>(M0, eaW, wrecW, PqP, PlP);
    phaseB_kernel<<<NROWS_Q/8, 256, 0, stream>>>(PqP, PlP, q_e, le_last,
                                                 ln_g, ln_b, W0, b0, W1, b1,
                                                 W_out, b_out, out);
}

// Round 12
// 193.892 us; speedup vs baseline: 1.3497x; 1.0086x over previous
//
#include <hip/hip_runtime.h>
#include <math.h>

// Problem constants
#define BB 32
#define SS 50
#define LL 16
#define CC 50
#define DD 64
#define NCH 13           // c-chunks of 4 rows (C=50 padded to 52)
#define H4 256
#define NROWS_Q (BB*SS)            // 1600
#define NROWS_L (BB*SS*LL)         // 25600

#define EA_ST 2176       // floats per (b,s) ea record: 17 slots * 128
#define W_ST  68         // floats per (b,om,s) w record: 17 * 4

// GEMM geometry for k0
#define RB 32                       // rows per block -> 900 blocks
#define NBLK_L (NROWS_L/RB)         // 800
#define NBLK_Q (NROWS_Q/RB)         // 50
#define NGB (NBLK_L + 2*NBLK_Q)     // 900

// phaseB k-batching: 16 k-rows per register batch
#define KBAT 16
#define NBAT (H4/KBAT)              // 16 batches — MUST cover all of H4

// Layout invariants shared by k0 (producer) and phaseA (consumer)
static_assert(EA_ST == 17*128, "ea record: 17 slots x 64 lanes x float2");
static_assert(W_ST == 17*4, "w record: 17 slots x 4 chunk-cols");
static_assert(SS == 50, "phaseA pipeline is hand-unrolled for SS=50 (48+2)");
static_assert(NROWS_L % RB == 0 && NROWS_Q % RB == 0, "GEMM row blocking");
static_assert(RB % 16 == 0, "l-row il-groups must not straddle blocks");
static_assert(NBAT*KBAT == H4 && NBAT % 2 == 0,
              "phaseB k-loop must cover ALL of H4 in pairs of batches");
static_assert(SS*DD % 4 == 0, "phaseA partial copy uses float4");

// ---------------- workspace layout (floats) ----------------
#define OFF_EA     ((size_t)0)
#define OFF_W      (OFF_EA + (size_t)NROWS_Q*EA_ST)            // +3,481,600
#define OFF_PQP    (OFF_W  + (size_t)BB*NCH*SS*W_ST)           // +1,414,400
#define OFF_PLP    (OFF_PQP + (size_t)NCH*BB*SS*DD)            // +1,331,200
#define OFF_QE     (OFF_PLP + (size_t)NCH*BB*SS*DD)            // +1,331,200
#define OFF_LELAST (OFF_QE + (size_t)NROWS_Q*DD)               // +102,400
// total = 7,763,200 floats = 29.6 MB

__device__ __forceinline__ float fast_sigmoid(float x) {
    return 1.f / (1.f + __expf(-x));
}
__device__ __forceinline__ float fast_tanh(float x) {
    // |x| small here (embeddings*W ~ O(0.1)); e^{2x} cannot overflow
    float t = __expf(2.f * x);
    return (t - 1.f) / (t + 1.f);
}

// =====================================================================
// K0 v4: BARRIER-FREE precompute GEMM. 900 blocks x 256 thr, 8 KB LDS.
// Each wave stages only ITS OWN 8 X-rows into LDS (wave-local ds
// ordering -> no __syncthreads anywhere). W is read directly from
// global per k-chunk: We/Wa[k][lane] are wave-coalesced 256B lines,
// K^T cols are contiguous Kmat rows (float4). We+Wa+K = 45 KB ->
// L1-resident after first touch. Lane owns output cols
// {lane, 64+lane, 128+lane} = (er, ad, score) — register-resident
// output feeds stage-2 directly. Fast-math transcendentals.
// =====================================================================
__global__ __launch_bounds__(256, 4) void k0_kernel(
    const int* __restrict__ qd, const int* __restrict__ qadx,
    const int* __restrict__ ld,
    const float* __restrict__ Kmat, const float* __restrict__ qemb,
    const float* __restrict__ qaemb,
    const float* __restrict__ We, const float* __restrict__ Wa,
    const float* __restrict__ be, const float* __restrict__ ba,
    float* __restrict__ eaW, float* __restrict__ wrecW,
    float* __restrict__ q_e_o, float* __restrict__ le_last)
{
    __shared__ float sX[RB*DD];         // 8 KB [32 rows][64 k]

    int tid = threadIdx.x;
    int bid = blockIdx.x;

    int bt, base;
    if (bid < NBLK_L)              { bt = 0; base = bid*RB; }
    else if (bid < NBLK_L+NBLK_Q)  { bt = 1; base = (bid-NBLK_L)*RB; }
    else                           { bt = 2; base = (bid-NBLK_L-NBLK_Q)*RB; }

    int lane = tid & 63, wvi = tid >> 6;
    int r0 = wvi * 8;                   // this wave's 8 rows

    // ---- stage THIS WAVE's 8 rows (wave-local; no barrier needed) ----
    {
        const int*   idsrc = (bt==0) ? ld : (bt==1) ? qd : qadx;
        const float* tab   = (bt==2) ? qaemb : qemb;
        #pragma unroll
        for (int i = 0; i < 2; ++i) {
            int f = i*64 + lane;        // 0..127
            int r = f >> 4;             // local row 0..7
            int q = f & 15;
            int id = idsrc[base + r0 + r];
            *(float4*)(sX + (r0+r)*64 + q*4) =
                *(const float4*)(tab + (size_t)id*DD + q*4);
        }
    }

    // W column pointers for this lane
    const float* weCol = We + lane;                       // We[k][lane], stride 64
    const float* waCol = Wa + lane;                       // Wa[k][lane]
    int krow = (lane < CC) ? lane : 0;                    // clamp (no OOB)
    const float* ksRow = Kmat + (size_t)krow*DD;          // Kmat[lane][k], contiguous

    float accE[8], accA[8], accS[8];
    #pragma unroll
    for (int r = 0; r < 8; ++r) { accE[r] = 0.f; accA[r] = 0.f; accS[r] = 0.f; }

    // ---- GEMM: 16 k-chunks of 4 ----
    #pragma unroll 4
    for (int k4 = 0; k4 < 16; ++k4) {
        float wE[4], wA4[4];
        #pragma unroll
        for (int kk = 0; kk < 4; ++kk) {
            wE[kk]  = weCol[(size_t)(k4*4+kk)*DD];
            wA4[kk] = waCol[(size_t)(k4*4+kk)*DD];
        }
        float4 wS = *(const float4*)(ksRow + k4*4);
        #pragma unroll
        for (int r = 0; r < 8; ++r) {
            float4 xv = *(const float4*)(sX + (r0+r)*64 + k4*4);
            accE[r] = fmaf(xv.x, wE[0], accE[r]);
            accE[r] = fmaf(xv.y, wE[1], accE[r]);
            accE[r] = fmaf(xv.z, wE[2], accE[r]);
            accE[r] = fmaf(xv.w, wE[3], accE[r]);
            accA[r] = fmaf(xv.x, wA4[0], accA[r]);
            accA[r] = fmaf(xv.y, wA4[1], accA[r]);
            accA[r] = fmaf(xv.z, wA4[2], accA[r]);
            accA[r] = fmaf(xv.w, wA4[3], accA[r]);
            accS[r] = fmaf(xv.x, wS.x, accS[r]);
            accS[r] = fmaf(xv.y, wS.y, accS[r]);
            accS[r] = fmaf(xv.z, wS.z, accS[r]);
            accS[r] = fmaf(xv.w, wS.w, accS[r]);
        }
    }

    // ---- stage 2: per-row nonlinearity + packing, straight from regs ----
    float bev = be[lane], bav = ba[lane];

    #pragma unroll
    for (int r = 0; r < 8; ++r) {
        int rr = r0 + r;
        int grow = base + rr;

        float s = (lane < CC) ? accS[r] : -1e30f;
        float mx = s;
        #pragma unroll
        for (int o = 32; o >= 1; o >>= 1) mx = fmaxf(mx, __shfl_xor(mx, o));
        float p = (lane < CC) ? __expf(s - mx) : 0.f;
        float sum = p;
        #pragma unroll
        for (int o = 32; o >= 1; o >>= 1) sum += __shfl_xor(sum, o);
        float wsm = p / sum;

        if (bt == 0) {
            float erv = fast_sigmoid(accE[r] + bev);
            float adv = fast_tanh(accA[r] + bav);
            int bs = grow >> 4, il = grow & 15;
            *(float2*)(eaW + (size_t)bs*EA_ST + il*128 + lane*2) =
                make_float2(erv, adv);
            int b = bs / SS, s2 = bs - b*SS;
            if (lane < 52) {
                int omx = lane >> 2, j = lane & 3;
                wrecW[(((size_t)(b*NCH + omx)*SS + s2)*17 + il)*4 + j] =
                    (lane < CC) ? wsm : 0.f;
            }
            if (il == LL-1) le_last[(size_t)bs*DD + lane] = sX[rr*64 + lane];
        } else if (bt == 1) {
            int qrow = grow;
            int b = qrow / SS, s2 = qrow - b*SS;
            if (lane < 52) {
                int omx = lane >> 2, j = lane & 3;
                wrecW[(((size_t)(b*NCH + omx)*SS + s2)*17 + 16)*4 + j] =
                    (lane < CC) ? wsm : 0.f;
            }
            q_e_o[(size_t)qrow*DD + lane] = sX[rr*64 + lane];
        } else {
            float erv = fast_sigmoid(accE[r] + bev);
            float adv = fast_tanh(accA[r] + bav);
            int qrow = grow;
            *(float2*)(eaW + (size_t)qrow*EA_ST + 2048 + lane*2) =
                make_float2(erv, adv);
        }
    }
}

// =====================================================================
// Phase A v4: sequential scan, 2-step-deep ea register pipeline
// (3 named buffers, unroll-by-3: 48 steps + 2-step epilogue).
// Partials -> LDS; one bulk float4 copy at end. No atomics, no VMEM
// stores in the loop. (unchanged from round 10)
// =====================================================================
__global__ __launch_bounds__(64) void phaseA_kernel(
    const float* __restrict__ M0,
    const float* __restrict__ ea, const float* __restrict__ wrec,
    float* __restrict__ PqP, float* __restrict__ PlP)
{
    int om   = blockIdx.x >> 5;     // 0..12
    int b    = blockIdx.x & 31;     // 0..31
    int lane = threadIdx.x;
    int c0   = om * 4;

    __shared__ __align__(16) float wbuf[2][W_ST];
    __shared__ __align__(16) float sPq[SS*DD];   // 12.8 KB
    __shared__ __align__(16) float sPl[SS*DD];   // 12.8 KB

    float M[4];
    #pragma unroll
    for (int i = 0; i < 4; ++i) {
        int c = c0 + i;
        M[i] = (c < CC) ? M0[c*DD + lane] : 0.f;
    }

    const float* eb = ea   + (size_t)b*SS*EA_ST + lane*2;
    const float* wb = wrec + (size_t)(b*NCH + om)*SS*W_ST;

    float2 eaA[17], eaB[17], eaC[17];
    float4 rw0, rw1, rw2;

    // ---- prologue ----
    #pragma unroll
    for (int il = 0; il < 17; ++il) eaA[il] = *(const float2*)(eb + il*128);
    #pragma unroll
    for (int il = 0; il < 17; ++il) eaB[il] = *(const float2*)(eb + EA_ST + il*128);
    if (lane < 17) {
        float4 w0 = *(const float4*)(wb + lane*4);
        *(float4*)&wbuf[0][lane*4] = w0;
        rw0 = *(const float4*)(wb + (size_t)W_ST + lane*4);
    }

    auto step = [&](int s, float2 (&cur)[17], float2 (&nxt)[17],
                    float4& rwW, float4& rwL, bool doLoad, bool doWrite) {
        if (doLoad && lane < 17)
            rwL = *(const float4*)(wb + (size_t)(s+2)*W_ST + lane*4);
        if (doLoad) {
            const float* eg = eb + (size_t)(s+2)*EA_ST;
            #pragma unroll
            for (int il = 0; il < 17; ++il)
                nxt[il] = *(const float2*)(eg + il*128);
        }
        if (doWrite && lane < 17)
            *(float4*)&wbuf[(s+1)&1][lane*4] = rwW;

        const float* wbp = &wbuf[s&1][0];
        float4 qw = *(const float4*)(wbp + 64);
        float qr;
        qr = qw.x * M[0];
        qr = fmaf(qw.y, M[1], qr);
        qr = fmaf(qw.z, M[2], qr);
        qr = fmaf(qw.w, M[3], qr);

        float a0 = 0.f, a1 = 0.f, a2 = 0.f, a3 = 0.f;
        #pragma unroll
        for (int il = 0; il < 16; ++il) {
            float4 w = *(const float4*)(wbp + il*4);
            float e = cur[il].x, a = cur[il].y;
            a0 = fmaf(w.x, M[0], a0);
            a1 = fmaf(w.y, M[1], a1);
            a2 = fmaf(w.z, M[2], a2);
            a3 = fmaf(w.w, M[3], a3);
            M[0] = fmaf(w.x, fmaf(-e, M[0], a), M[0]);
            M[1] = fmaf(w.y, fmaf(-e, M[1], a), M[1]);
            M[2] = fmaf(w.z, fmaf(-e, M[2], a), M[2]);
            M[3] = fmaf(w.w, fmaf(-e, M[3], a), M[3]);
        }

        sPq[s*DD + lane] = qr;
        sPl[s*DD + lane] = (a0 + a1) + (a2 + a3);

        {
            float e = cur[16].x, a = cur[16].y;
            M[0] = fmaf(qw.x, fmaf(-e, M[0], a), M[0]);
            M[1] = fmaf(qw.y, fmaf(-e, M[1], a), M[1]);
            M[2] = fmaf(qw.z, fmaf(-e, M[2], a), M[2]);
            M[3] = fmaf(qw.w, fmaf(-e, M[3], a), M[3]);
        }
    };

    for (int s = 0; s < 48; s += 3) {
        step(s,     eaA, eaC, rw0, rw1, true, true);
        step(s + 1, eaB, eaA, rw1, rw2, true, true);
        step(s + 2, eaC, eaB, rw2, rw0, true, true);
    }
    step(48, eaA, eaC, rw0, rw1, false, true);
    step(49, eaB, eaA, rw1, rw2, false, false);

    // ---- epilogue: bulk coalesced copy LDS partials -> global ----
    float* pqo = PqP + (size_t)(om*BB + b)*SS*DD;
    float* plo = PlP + (size_t)(om*BB + b)*SS*DD;
    for (int f = lane; f < SS*DD/4; f += 64) {
        *(float4*)(pqo + f*4) = *(const float4*)(sPq + f*4);
        *(float4*)(plo + f*4) = *(const float4*)(sPl + f*4);
    }
}

// =====================================================================
// Phase B v3.2: mastery (13-way partial sum) -> LN -> MLP -> out.
// (unchanged from round 9)
// =====================================================================
__global__ __launch_bounds__(256) void phaseB_kernel(
    const float* __restrict__ PqP, const float* __restrict__ PlP,
    const float* __restrict__ q_e_i, const float* __restrict__ le_last,
    const float* __restrict__ ln_g, const float* __restrict__ ln_b,
    const float* __restrict__ W0, const float* __restrict__ b0,
    const float* __restrict__ W1, const float* __restrict__ b1,
    const float* __restrict__ Wout, const float* __restrict__ bout,
    float* __restrict__ out)
{
    __shared__ float m[8][H4];
    __shared__ float h[8][H4];
    __shared__ float red[8][4];

    int j = threadIdx.x;
    int g0 = blockIdx.x * 8;
    int lane = j & 63, wv = j >> 6;

    int seg = j >> 6, dd = j & 63;
    #pragma unroll
    for (int r = 0; r < 8; ++r) {
        int g = g0 + r;
        float v;
        if (seg == 0) {
            v = 0.f;
            #pragma unroll
            for (int om = 0; om < NCH; ++om)
                v += PqP[((size_t)om*BB*SS + g)*DD + dd];
        } else if (seg == 1) {
            v = q_e_i[(size_t)g*DD + dd];
        } else if (seg == 2) {
            v = 0.f;
            #pragma unroll
            for (int om = 0; om < NCH; ++om)
                v += PlP[((size_t)om*BB*SS + g)*DD + dd];
        } else {
            v = le_last[(size_t)g*DD + dd];
        }
        m[r][j] = v;
    }
    __syncthreads();

    #pragma unroll
    for (int rr = 0; rr < 2; ++rr) {
        int r = wv + rr*4;
        float4 v4 = *(((const float4*)&m[r][0]) + lane);
        float s1 = v4.x + v4.y + v4.z + v4.w;
        float s2 = v4.x*v4.x + v4.y*v4.y + v4.z*v4.z + v4.w*v4.w;
        #pragma unroll
        for (int o = 32; o >= 1; o >>= 1) {
            s1 += __shfl_xor(s1, o);
            s2 += __shfl_xor(s2, o);
        }
        float mu  = s1 * (1.f/256.f);
        float var = s2 * (1.f/256.f) - mu*mu;
        float is  = rsqrtf(var + 1e-5f);
        float4 g4 = *(((const float4*)ln_g) + lane);
        float4 b4 = *(((const float4*)ln_b) + lane);
        float4 o4;
        o4.x = (v4.x - mu)*is*g4.x + b4.x;
        o4.y = (v4.y - mu)*is*g4.y + b4.y;
        o4.z = (v4.z - mu)*is*g4.z + b4.z;
        o4.w = (v4.w - mu)*is*g4.w + b4.w;
        *(((float4*)&m[r][0]) + lane) = o4;
    }
    __syncthreads();

    const float* Wp = W0 + j;
    float acc[8];
    {
        float bj = b0[j];
        #pragma unroll
        for (int r = 0; r < 8; ++r) acc[r] = bj;
    }
    {
        float wA[KBAT], wB[KBAT];
        #pragma unroll
        for (int t = 0; t < KBAT; ++t) wA[t] = Wp[(size_t)t*H4];
        #pragma unroll 1
        for (int kb = 0; kb < NBAT; kb += 2) {
            #pragma unroll
            for (int t = 0; t < KBAT; ++t)
                wB[t] = Wp[(size_t)((kb+1)*KBAT + t)*H4];
            #pragma unroll
            for (int t4 = 0; t4 < KBAT/4; ++t4) {
                #pragma unroll
                for (int r = 0; r < 8; ++r) {
                    float4 mv = *(const float4*)&m[r][kb*KBAT + t4*4];
                    acc[r] = fmaf(mv.x, wA[t4*4+0], acc[r]);
                    acc[r] = fmaf(mv.y, wA[t4*4+1], acc[r]);
                    acc[r] = fmaf(mv.z, wA[t4*4+2], acc[r]);
                    acc[r] = fmaf(mv.w, wA[t4*4+3], acc[r]);
                }
            }
            if (kb + 2 < NBAT) {
                #pragma unroll
                for (int t = 0; t < KBAT; ++t)
                    wA[t] = Wp[(size_t)((kb+2)*KBAT + t)*H4];
            }
            #pragma unroll
            for (int t4 = 0; t4 < KBAT/4; ++t4) {
                #pragma unroll
                for (int r = 0; r < 8; ++r) {
                    float4 mv = *(const float4*)&m[r][(kb+1)*KBAT + t4*4];
                    acc[r] = fmaf(mv.x, wB[t4*4+0], acc[r]);
                    acc[r] = fmaf(mv.y, wB[t4*4+1], acc[r]);
                    acc[r] = fmaf(mv.z, wB[t4*4+2], acc[r]);
                    acc[r] = fmaf(mv.w, wB[t4*4+3], acc[r]);
                }
            }
        }
    }
    #pragma unroll
    for (int r = 0; r < 8; ++r) h[r][j] = fmaxf(acc[r], 0.f);
    __syncthreads();

    const float* Wp1 = W1 + j;
    float a2[8];
    {
        float bj = b1[j];
        #pragma unroll
        for (int r = 0; r < 8; ++r) a2[r] = bj;
    }
    {
        float wA[KBAT], wB[KBAT];
        #pragma unroll
        for (int t = 0; t < KBAT; ++t) wA[t] = Wp1[(size_t)t*H4];
        #pragma unroll 1
        for (int kb = 0; kb < NBAT; kb += 2) {
            #pragma unroll
            for (int t = 0; t < KBAT; ++t)
                wB[t] = Wp1[(size_t)((kb+1)*KBAT + t)*H4];
            #pragma unroll
            for (int t4 = 0; t4 < KBAT/4; ++t4) {
                #pragma unroll
                for (int r = 0; r < 8; ++r) {
                    float4 hv = *(const float4*)&h[r][kb*KBAT + t4*4];
                    a2[r] = fmaf(hv.x, wA[t4*4+0], a2[r]);
                    a2[r] = fmaf(hv.y, wA[t4*4+1], a2[r]);
                    a2[r] = fmaf(hv.z, wA[t4*4+2], a2[r]);
                    a2[r] = fmaf(hv.w, wA[t4*4+3], a2[r]);
                }
            }
            if (kb + 2 < NBAT) {
                #pragma unroll
                for (int t = 0; t < KBAT; ++t)
                    wA[t] = Wp1[(size_t)((kb+2)*KBAT + t)*H4];
            }
            #pragma unroll
            for (int t4 = 0; t4 < KBAT/4; ++t4) {
                #pragma unroll
                for (int r = 0; r < 8; ++r) {
                    float4 hv = *(const float4*)&h[r][(kb+1)*KBAT + t4*4];
                    a2[r] = fmaf(hv.x, wB[t4*4+0], a2[r]);
                    a2[r] = fmaf(hv.y, wB[t4*4+1], a2[r]);
                    a2[r] = fmaf(hv.z, wB[t4*4+2], a2[r]);
                    a2[r] = fmaf(hv.w, wB[t4*4+3], a2[r]);
                }
            }
        }
    }

    float wo = Wout[j];
    #pragma unroll
    for (int r = 0; r < 8; ++r) {
        float v = a2[r] * wo;
        #pragma unroll
        for (int o = 32; o >= 1; o >>= 1) v += __shfl_xor(v, o);
        if (lane == 0) red[r][wv] = v;
    }
    __syncthreads();
    if (j < 8) {
        float t = red[j][0] + red[j][1] + red[j][2] + red[j][3] + bout[0];
        out[g0 + j] = 1.f / (1.f + expf(-t));
    }
}

// =====================================================================
extern "C" void kernel_launch(void* const* d_in, const int* in_sizes, int n_in,
                              void* d_out, int out_size, void* d_ws, size_t ws_size,
                              hipStream_t stream)
{
    const int*   q_data  = (const int*)  d_in[0];
    const int*   qa_data = (const int*)  d_in[1];
    const int*   l_data  = (const int*)  d_in[2];
    // d_in[3] users: unused by reference forward
    const float* Kmat    = (const float*)d_in[4];
    const float* q_embed = (const float*)d_in[5];
    const float* qa_embed= (const float*)d_in[6];
    // d_in[7] u_embed: unused by reference forward
    const float* M0      = (const float*)d_in[8];
    const float* W_e     = (const float*)d_in[9];
    const float* b_e     = (const float*)d_in[10];
    const float* W_a     = (const float*)d_in[11];
    const float* b_a     = (const float*)d_in[12];
    const float* ln_g    = (const float*)d_in[13];
    const float* ln_b    = (const float*)d_in[14];
    const float* W0      = (const float*)d_in[15];
    const float* b0      = (const float*)d_in[16];
    const float* W1      = (const float*)d_in[17];
    const float* b1      = (const float*)d_in[18];
    const float* W_out   = (const float*)d_in[19];
    const float* b_out   = (const float*)d_in[20];

    float* ws = (float*)d_ws;
    float* eaW     = ws + OFF_EA;
    float* wrecW   = ws + OFF_W;
    float* PqP     = ws + OFF_PQP;
    float* PlP     = ws + OFF_PLP;
    float* q_e     = ws + OFF_QE;
    float* le_last = ws + OFF_LELAST;

    float* out = (float*)d_out;

    k0_kernel<<<NGB, 256, 0, stream>>>(q_data, qa_data, l_data,
                                       Kmat, q_embed, qa_embed,
                                       W_e, W_a, b_e, b_a,
                                       eaW, wrecW,
                                       q_e, le_last);
    phaseA_kernel<<<BB*NCH, 64, 0, stream>>>(M0, eaW, wrecW, PqP, PlP);
    phaseB_kernel<<<NROWS_Q/8, 256, 0, stream>>>(PqP, PlP, q_e, le_last,
                                                 ln_g, ln_b, W0, b0, W1, b1,
                                                 W_out, b_out, out);
}